// Round 8
// baseline (2903.388 us; speedup 1.0000x reference)
//
#include <hip/hip_runtime.h>

typedef __bf16 bf16_t;
typedef bf16_t bf16x8 __attribute__((ext_vector_type(8)));
typedef bf16_t bf16x4 __attribute__((ext_vector_type(4)));
typedef float  f32x4  __attribute__((ext_vector_type(4)));

#define NN   81
#define BB   512
#define BN   41472          // 512*81
#define EE   1620

__device__ __forceinline__ int swz(int r, int k) {
    return (r << 7) + ((((k >> 3) ^ (r & 7)) << 3) | (k & 7));
}

// packed-weight element offset for W'[n][k] (128x128): one coalesced 16B load
// per mfma B-fragment per lane
__device__ __forceinline__ int wpack(int n, int k) {
    return ((n >> 6) << 13) + (((((k >> 5) << 2) + ((n >> 4) & 3))) << 9)
         + (((((k >> 3) & 3) << 4) + (n & 15)) << 3) + (k & 7);
}

// pack two f32 -> bf16x2, round-half-up: 2 adds + 1 v_perm
__device__ __forceinline__ unsigned pkbf(float lo, float hi) {
    unsigned a = __float_as_uint(lo) + 0x8000u;
    unsigned b = __float_as_uint(hi) + 0x8000u;
    return __builtin_amdgcn_perm(b, a, 0x07060302);
}

// truncating pack (1 v_perm) — intra-step activations only
__device__ __forceinline__ unsigned pkbf_t(float lo, float hi) {
    return __builtin_amdgcn_perm(__float_as_uint(hi), __float_as_uint(lo), 0x07060302);
}

// bf16x2 dword (p,q) -> relu(p+q) packed
__device__ __forceinline__ unsigned addrelu_pk(unsigned pd, unsigned qd) {
    float p0 = __uint_as_float(pd << 16), p1 = __uint_as_float(pd & 0xffff0000u);
    float q0 = __uint_as_float(qd << 16), q1 = __uint_as_float(qd & 0xffff0000u);
    return pkbf(fmaxf(p0 + q0, 0.f), fmaxf(p1 + q1, 0.f));
}

// ---------------- 128-wide GEMM pieces ----------------
__device__ __forceinline__ void stage_act_f32(bf16_t* act, const float* __restrict__ src, int tid) {
    for (int ch = tid; ch < 2048; ch += 256) {
        int r = ch >> 4, p = ch & 15;
        const float4 a = *(const float4*)(src + (size_t)r * 128 + p * 8);
        const float4 b = *(const float4*)(src + (size_t)r * 128 + p * 8 + 4);
        uint4 o;
        o.x = pkbf(a.x, a.y); o.y = pkbf(a.z, a.w);
        o.z = pkbf(b.x, b.y); o.w = pkbf(b.z, b.w);
        *(uint4*)&act[swz(r, p << 3)] = o;
    }
}

// zero-init 128x128 (prep GEMM)
__device__ __forceinline__ void gemm128s(f32x4 (&acc)[4][4], const bf16_t* act,
                                         const bf16_t* __restrict__ Wp,
                                         int wm, int wn, int lane, int lrow, int q) {
    f32x4 z = {0.f, 0.f, 0.f, 0.f};
    #pragma unroll
    for (int i = 0; i < 4; i++)
        #pragma unroll
        for (int j = 0; j < 4; j++) acc[i][j] = z;
    const bf16_t* wbase = Wp + (wn << 13) + (lane << 3);
    #pragma unroll
    for (int k0 = 0; k0 < 128; k0 += 32) {
        bf16x8 af[4], wf[4];
        #pragma unroll
        for (int mt = 0; mt < 4; mt++)
            af[mt] = *(const bf16x8*)&act[swz(wm * 64 + mt * 16 + lrow, k0 + q * 8)];
        #pragma unroll
        for (int nt = 0; nt < 4; nt++)
            wf[nt] = *(const bf16x8*)(wbase + ((((k0 >> 5) << 2) + nt) << 9));
        #pragma unroll
        for (int nt = 0; nt < 4; nt++)
            #pragma unroll
            for (int mt = 0; mt < 4; mt++)
                acc[nt][mt] = __builtin_amdgcn_mfma_f32_16x16x32_bf16(wf[nt], af[mt], acc[nt][mt], 0, 0, 0);
    }
}

// bias-init variant (edge kernel); wm may be 0..3 (M=256 blocks)
__device__ __forceinline__ void gemm128b(f32x4 (&acc)[4][4], const bf16_t* act,
                                         const bf16_t* __restrict__ Wp,
                                         const float4 (&binit)[4],
                                         int wm, int wn, int lane, int lrow, int q) {
    #pragma unroll
    for (int nt = 0; nt < 4; nt++) {
        f32x4 bv; bv[0] = binit[nt].x; bv[1] = binit[nt].y; bv[2] = binit[nt].z; bv[3] = binit[nt].w;
        #pragma unroll
        for (int mt = 0; mt < 4; mt++) acc[nt][mt] = bv;
    }
    const bf16_t* wbase = Wp + (wn << 13) + (lane << 3);
    #pragma unroll
    for (int k0 = 0; k0 < 128; k0 += 32) {
        bf16x8 af[4], wf[4];
        #pragma unroll
        for (int mt = 0; mt < 4; mt++)
            af[mt] = *(const bf16x8*)&act[swz(wm * 64 + mt * 16 + lrow, k0 + q * 8)];
        #pragma unroll
        for (int nt = 0; nt < 4; nt++)
            wf[nt] = *(const bf16x8*)(wbase + ((((k0 >> 5) << 2) + nt) << 9));
        #pragma unroll
        for (int nt = 0; nt < 4; nt++)
            #pragma unroll
            for (int mt = 0; mt < 4; mt++)
                acc[nt][mt] = __builtin_amdgcn_mfma_f32_16x16x32_bf16(wf[nt], af[mt], acc[nt][mt], 0, 0, 0);
    }
}

// relu writeback (bias already in acc), truncating pack
__device__ __forceinline__ void wb_pk(bf16_t* act, f32x4 (&acc)[4][4],
                                      int wm, int wn, int lrow, int q) {
    #pragma unroll
    for (int nt = 0; nt < 4; nt++) {
        int nb = wn * 64 + nt * 16 + q * 4;
        #pragma unroll
        for (int mt = 0; mt < 4; mt++) {
            int m = wm * 64 + mt * 16 + lrow;
            uint2 u;
            u.x = pkbf_t(fmaxf(acc[nt][mt][0], 0.f), fmaxf(acc[nt][mt][1], 0.f));
            u.y = pkbf_t(fmaxf(acc[nt][mt][2], 0.f), fmaxf(acc[nt][mt][3], 0.f));
            *(uint2*)&act[swz(m, nb)] = u;
        }
    }
}

// ---------------- node-kernel GEMM: wave tile 32(M) x 32(N) ----------------
__device__ __forceinline__ void gemm32s(f32x4 (&acc)[2][2], const bf16_t* act,
                                        const bf16_t* __restrict__ Wp,
                                        int wid, int lane, int lrow, int q, bool zero) {
    if (zero) {
        f32x4 z = {0.f, 0.f, 0.f, 0.f};
        acc[0][0] = z; acc[0][1] = z; acc[1][0] = z; acc[1][1] = z;
    }
    int wn = wid >> 1, ntb = (wid & 1) << 1;
    const bf16_t* wbase = Wp + (wn << 13) + (lane << 3);
    #pragma unroll
    for (int k0 = 0; k0 < 128; k0 += 32) {
        bf16x8 af[2], wf[2];
        af[0] = *(const bf16x8*)&act[swz(lrow, k0 + q * 8)];
        af[1] = *(const bf16x8*)&act[swz(16 + lrow, k0 + q * 8)];
        wf[0] = *(const bf16x8*)(wbase + ((((k0 >> 5) << 2) + ntb) << 9));
        wf[1] = *(const bf16x8*)(wbase + ((((k0 >> 5) << 2) + ntb + 1) << 9));
        #pragma unroll
        for (int nt = 0; nt < 2; nt++)
            #pragma unroll
            for (int mt = 0; mt < 2; mt++)
                acc[nt][mt] = __builtin_amdgcn_mfma_f32_16x16x32_bf16(wf[nt], af[mt], acc[nt][mt], 0, 0, 0);
    }
}

__device__ __forceinline__ void wb32(bf16_t* act, f32x4 (&acc)[2][2], const float* __restrict__ bias,
                                     int colb, int lrow, int q) {
    #pragma unroll
    for (int nt = 0; nt < 2; nt++) {
        int nb = colb + nt * 16 + q * 4;
        float4 b4 = *(const float4*)&bias[nb];
        #pragma unroll
        for (int mt = 0; mt < 2; mt++) {
            int m = mt * 16 + lrow;
            uint2 u;
            u.x = pkbf_t(fmaxf(acc[nt][mt][0] + b4.x, 0.f), fmaxf(acc[nt][mt][1] + b4.y, 0.f));
            u.y = pkbf_t(fmaxf(acc[nt][mt][2] + b4.z, 0.f), fmaxf(acc[nt][mt][3] + b4.w, 0.f));
            *(uint2*)&act[swz(m, nb)] = u;
        }
    }
}

// ---------------- prep kernels ----------------

__global__ __launch_bounds__(256) void k_embed(const float* __restrict__ x, const float* __restrict__ W_in,
                                               const float* __restrict__ b_in, const float* __restrict__ pos,
                                               float* __restrict__ h) {
    int idx = blockIdx.x * 256 + threadIdx.x;   // < BN*128
    int row = idx >> 7, col = idx & 127;
    int n = row % NN;
    const float* xr = x + (size_t)row * 10;
    float s = b_in[col] + pos[n * 128 + col];
    #pragma unroll
    for (int k = 0; k < 10; k++) s += xr[k] * W_in[k * 128 + col];
    h[idx] = s;
}

struct PackArgs { const float* s[9]; };

__global__ __launch_bounds__(256) void k_pack_all(PackArgs pa, bf16_t* __restrict__ dst) {
    const int slot[9] = {0, 1, 2, 3, 4, 6, 7, 8, 9};
    int idx = blockIdx.x * 256 + threadIdx.x;   // < 9*16384
    int w = idx >> 14, r = idx & 16383;
    int n = r >> 7, k = r & 127;
    dst[slot[w] * 16384 + wpack(n, k)] = (bf16_t)pa.s[w][k * 128 + n];
}

__global__ __launch_bounds__(256) void k_fuse(const float* __restrict__ mW3, const float* __restrict__ nW0,
                                              bf16_t* __restrict__ Ft) {
    int idx = blockIdx.x * 256 + threadIdx.x;   // < 16384
    int n = idx >> 7, k = idx & 127;
    float s = 0.f;
    for (int j = 0; j < 128; j++) s += mW3[k * 128 + j] * nW0[(256 + j) * 128 + n];
    Ft[wpack(n, k)] = (bf16_t)s;
}

__global__ __launch_bounds__(128) void k_bias(const float* __restrict__ nb0, const float* __restrict__ mb3,
                                              const float* __restrict__ nW0, float* __restrict__ bfix) {
    int n = threadIdx.x;
    float s = 0.f;
    for (int j = 0; j < 128; j++) s += mb3[j] * nW0[(256 + j) * 128 + n];
    bfix[n] = nb0[n] + 20.f * s;
}

// one launch does C2 (f32, bias=bfix), P (bf16), Q' (bf16, bias=mb0)
__global__ __launch_bounds__(256, 2) void k_simple3(const float* __restrict__ in,
                                                    const bf16_t* __restrict__ Wp,
                                                    const float* __restrict__ bfix,
                                                    const float* __restrict__ mb0,
                                                    float* __restrict__ C2,
                                                    bf16_t* __restrict__ Pd,
                                                    bf16_t* __restrict__ Qd) {
    __shared__ __align__(16) bf16_t act[16384];
    int tid = threadIdx.x;
    int sel = blockIdx.x / 324, blk = blockIdx.x - sel * 324;
    size_t i0 = (size_t)blk * 128;
    int lane = tid & 63, wid = tid >> 6;
    int wm = wid >> 1, wn = wid & 1, lrow = lane & 15, q = lane >> 4;

    stage_act_f32(act, in + i0 * 128, tid);
    __syncthreads();
    const bf16_t* W = Wp + (sel == 0 ? 9 * 16384 : (sel == 1 ? 0 : 16384));
    f32x4 acc[4][4];
    gemm128s(acc, act, W, wm, wn, lane, lrow, q);
    #pragma unroll
    for (int nt = 0; nt < 4; nt++) {
        int nb = wn * 64 + nt * 16 + q * 4;
        float4 b4 = (sel == 0) ? *(const float4*)&bfix[nb]
                  : (sel == 2) ? *(const float4*)&mb0[nb]
                               : make_float4(0.f, 0.f, 0.f, 0.f);
        #pragma unroll
        for (int mt = 0; mt < 4; mt++) {
            int m = wm * 64 + mt * 16 + lrow;
            float v0 = acc[nt][mt][0] + b4.x, v1 = acc[nt][mt][1] + b4.y;
            float v2 = acc[nt][mt][2] + b4.z, v3 = acc[nt][mt][3] + b4.w;
            if (sel == 0) {
                float4 o; o.x = v0; o.y = v1; o.z = v2; o.w = v3;
                *(float4*)(C2 + (i0 + m) * 128 + nb) = o;
            } else {
                uint2 u; u.x = pkbf(v0, v1); u.y = pkbf(v2, v3);
                bf16_t* dst = (sel == 1) ? Pd : Qd;
                *(uint2*)(dst + (i0 + m) * 128 + nb) = u;
            }
        }
    }
}

// ---------------- edge kernel: M=256 blocks, 8 waves, 2 blocks/CU ----------------
// Block: 240 edge rows (12 dst nodes; last block 180 rows / 9 nodes), padded to 256.
// Wave (wm 0..3, wn 0..1) computes rows [wm*64,+64) x features [wn*64,+64).
__global__ __launch_bounds__(512, 2) void k_edge(const bf16_t* __restrict__ P, const bf16_t* __restrict__ Q,
                                                 const int* __restrict__ src, const bf16_t* __restrict__ Wp,
                                                 const float* __restrict__ mb1, const float* __restrict__ mb2,
                                                 bf16_t* __restrict__ SA) {
    __shared__ __align__(16) bf16_t act[32768];   // 256 rows x 128
    int tid = threadIdx.x;
    int g = blockIdx.x, b = blockIdx.y;
    int e0 = g * 240, n0 = g * 12;
    int nreal = (e0 + 240 <= EE) ? 240 : (EE - e0);   // 240 or 180
    int lane = tid & 63, wid = tid >> 6;
    int wm = wid >> 1, wn = wid & 1, lrow = lane & 15, q = lane >> 4;

    float4 b1[4], b2[4];
    #pragma unroll
    for (int nt = 0; nt < 4; nt++) {
        b1[nt] = *(const float4*)&mb1[wn * 64 + nt * 16 + q * 4];
        b2[nt] = *(const float4*)&mb2[wn * 64 + nt * 16 + q * 4];
    }

    // layer-0: act0 = relu(P[src] + Q'[dst]) (Q' has +mb0 folded), packed math
    for (int ch = tid; ch < 4096; ch += 512) {
        int r = ch >> 4, p = ch & 15;
        uint4 o;
        if (r < nreal) {
            int e = e0 + r;
            int sn = src[e];
            int dn = n0 + r / 20;
            uint4 pv = *(const uint4*)(P + (((size_t)b * NN + sn) << 7) + (p << 3));
            uint4 qv = *(const uint4*)(Q + (((size_t)b * NN + dn) << 7) + (p << 3));
            o.x = addrelu_pk(pv.x, qv.x);
            o.y = addrelu_pk(pv.y, qv.y);
            o.z = addrelu_pk(pv.z, qv.z);
            o.w = addrelu_pk(pv.w, qv.w);
        } else {
            o.x = 0u; o.y = 0u; o.z = 0u; o.w = 0u;
        }
        *(uint4*)&act[swz(r, p << 3)] = o;
    }
    __syncthreads();

    f32x4 acc[4][4];
    gemm128b(acc, act, Wp + 2 * 16384, b1, wm, wn, lane, lrow, q);   // act0 @ mW1 + mb1
    __syncthreads();
    wb_pk(act, acc, wm, wn, lrow, q);                                // act1 = relu
    __syncthreads();
    gemm128b(acc, act, Wp + 3 * 16384, b2, wm, wn, lane, lrow, q);   // act1 @ mW2 + mb2
    __syncthreads();
    wb_pk(act, acc, wm, wn, lrow, q);                                // act2 = relu
    __syncthreads();

    // SA[b][n0+j][c] = sum of act2 over the node's 20 edges (2-thread split)
    if (tid < 384) {
        int j = tid >> 5;              // node 0..11
        int sub = tid & 31;
        int rr = sub >> 1;             // 8-feature chunk
        int half = sub & 1;
        int nodes = nreal / 20;        // 12 or 9
        if (j < nodes) {
            float s0 = 0.f, s1 = 0.f, s2 = 0.f, s3 = 0.f, s4 = 0.f, s5 = 0.f, s6 = 0.f, s7 = 0.f;
            #pragma unroll
            for (int i = 0; i < 10; i++) {
                int m = 20 * j + half * 10 + i;
                bf16x8 v = *(const bf16x8*)&act[swz(m, rr << 3)];
                s0 += (float)v[0]; s1 += (float)v[1]; s2 += (float)v[2]; s3 += (float)v[3];
                s4 += (float)v[4]; s5 += (float)v[5]; s6 += (float)v[6]; s7 += (float)v[7];
            }
            s0 += __shfl_xor(s0, 1); s1 += __shfl_xor(s1, 1);
            s2 += __shfl_xor(s2, 1); s3 += __shfl_xor(s3, 1);
            s4 += __shfl_xor(s4, 1); s5 += __shfl_xor(s5, 1);
            s6 += __shfl_xor(s6, 1); s7 += __shfl_xor(s7, 1);
            if (half == 0) {
                uint4 o;
                o.x = pkbf(s0, s1); o.y = pkbf(s2, s3);
                o.z = pkbf(s4, s5); o.w = pkbf(s6, s7);
                *(uint4*)(SA + (((size_t)b * NN + n0 + j) << 7) + (rr << 3)) = o;
            }
        }
    }
}

// ---------------- node kernel: M=32, 4 waves x N=32, separate SA buffer ----------------
__global__ __launch_bounds__(256, 4) void k_node(float* __restrict__ h, const bf16_t* __restrict__ SA,
                                                 const float* __restrict__ C2, const bf16_t* __restrict__ Wp,
                                                 const float* __restrict__ nb1, const float* __restrict__ nb2,
                                                 const float* __restrict__ nb3, const float* __restrict__ ln_g,
                                                 const float* __restrict__ ln_b, const float* __restrict__ mb0,
                                                 bf16_t* __restrict__ Pd, bf16_t* __restrict__ Qd) {
    __shared__ __align__(16) bf16_t act[4096];   // 32 rows x 128
    __shared__ __align__(16) bf16_t sab[4096];   // staged SA
    __shared__ float st[256];                    // 32 rows x 4 waves x {s1,s2}
    int tid = threadIdx.x;
    size_t i0 = (size_t)blockIdx.x * 32;
    int lane = tid & 63, wid = tid >> 6;
    int lrow = lane & 15, q = lane >> 4;
    int colb = wid * 32;

    // stage h (f32->bf16, packed) and SA (raw copy) in one pass
    for (int ch = tid; ch < 1024; ch += 256) {
        if (ch < 512) {
            int r = ch >> 4, p = ch & 15;
            const float4 a = *(const float4*)(h + (i0 + r) * 128 + (p << 3));
            const float4 c = *(const float4*)(h + (i0 + r) * 128 + (p << 3) + 4);
            uint4 o;
            o.x = pkbf(a.x, a.y); o.y = pkbf(a.z, a.w);
            o.z = pkbf(c.x, c.y); o.w = pkbf(c.z, c.w);
            *(uint4*)&act[swz(r, p << 3)] = o;
        } else {
            int r = (ch - 512) >> 4, p = ch & 15;
            *(uint4*)&sab[swz(r, p << 3)] = *(const uint4*)(SA + (i0 + r) * 128 + (p << 3));
        }
    }
    __syncthreads();
    f32x4 acc[2][2];
    gemm32s(acc, act, Wp + 4 * 16384, wid, lane, lrow, q, true);     // h @ nW0a
    gemm32s(acc, sab, Wp + 5 * 16384, wid, lane, lrow, q, false);    // + SA @ Ft
    __syncthreads();
    // u0 = relu(acc + C2)
    #pragma unroll
    for (int nt = 0; nt < 2; nt++) {
        int nb = colb + nt * 16 + q * 4;
        #pragma unroll
        for (int mt = 0; mt < 2; mt++) {
            int m = mt * 16 + lrow;
            float4 c4 = *(const float4*)(C2 + (i0 + m) * 128 + nb);
            uint2 u;
            u.x = pkbf_t(fmaxf(acc[nt][mt][0] + c4.x, 0.f), fmaxf(acc[nt][mt][1] + c4.y, 0.f));
            u.y = pkbf_t(fmaxf(acc[nt][mt][2] + c4.z, 0.f), fmaxf(acc[nt][mt][3] + c4.w, 0.f));
            *(uint2*)&act[swz(m, nb)] = u;
        }
    }
    __syncthreads();
    gemm32s(acc, act, Wp + 6 * 16384, wid, lane, lrow, q, true);     // nW1
    __syncthreads();
    wb32(act, acc, nb1, colb, lrow, q);
    __syncthreads();
    gemm32s(acc, act, Wp + 7 * 16384, wid, lane, lrow, q, true);     // nW2
    __syncthreads();
    wb32(act, acc, nb2, colb, lrow, q);
    __syncthreads();
    gemm32s(acc, act, Wp + 8 * 16384, wid, lane, lrow, q, true);     // nW3

    // residual v = acc + nb3 + h, LN stats
    float s1[2] = {0.f, 0.f}, s2[2] = {0.f, 0.f};
    #pragma unroll
    for (int nt = 0; nt < 2; nt++) {
        int nb = colb + nt * 16 + q * 4;
        float4 b4 = *(const float4*)&nb3[nb];
        #pragma unroll
        for (int mt = 0; mt < 2; mt++) {
            int m = mt * 16 + lrow;
            float4 h4 = *(const float4*)(h + (i0 + m) * 128 + nb);
            float v0 = acc[nt][mt][0] + b4.x + h4.x;
            float v1 = acc[nt][mt][1] + b4.y + h4.y;
            float v2 = acc[nt][mt][2] + b4.z + h4.z;
            float v3 = acc[nt][mt][3] + b4.w + h4.w;
            acc[nt][mt][0] = v0; acc[nt][mt][1] = v1;
            acc[nt][mt][2] = v2; acc[nt][mt][3] = v3;
            s1[mt] += v0 + v1 + v2 + v3;
            s2[mt] += v0 * v0 + v1 * v1 + v2 * v2 + v3 * v3;
        }
    }
    #pragma unroll
    for (int mt = 0; mt < 2; mt++) {
        float a = s1[mt], c = s2[mt];
        a += __shfl_xor(a, 16); c += __shfl_xor(c, 16);
        a += __shfl_xor(a, 32); c += __shfl_xor(c, 32);
        s1[mt] = a; s2[mt] = c;
    }
    if (q == 0) {
        #pragma unroll
        for (int mt = 0; mt < 2; mt++) {
            st[(mt * 16 + lrow) * 8 + wid * 2 + 0] = s1[mt];
            st[(mt * 16 + lrow) * 8 + wid * 2 + 1] = s2[mt];
        }
    }
    __syncthreads();
    float mu[2], rs[2];
    #pragma unroll
    for (int mt = 0; mt < 2; mt++) {
        int m = mt * 16 + lrow;
        float a = st[m * 8 + 0] + st[m * 8 + 2] + st[m * 8 + 4] + st[m * 8 + 6];
        float c = st[m * 8 + 1] + st[m * 8 + 3] + st[m * 8 + 5] + st[m * 8 + 7];
        a *= (1.f / 128.f); c *= (1.f / 128.f);
        mu[mt] = a;
        rs[mt] = rsqrtf(c - a * a + 1e-5f);
    }
    // LN apply -> h (f32) and act (bf16 for P/Q gemms)
    #pragma unroll
    for (int nt = 0; nt < 2; nt++) {
        int nb = colb + nt * 16 + q * 4;
        float4 g4 = *(const float4*)&ln_g[nb];
        float4 bb4 = *(const float4*)&ln_b[nb];
        #pragma unroll
        for (int mt = 0; mt < 2; mt++) {
            int m = mt * 16 + lrow;
            float4 o4;
            o4.x = (acc[nt][mt][0] - mu[mt]) * rs[mt] * g4.x + bb4.x;
            o4.y = (acc[nt][mt][1] - mu[mt]) * rs[mt] * g4.y + bb4.y;
            o4.z = (acc[nt][mt][2] - mu[mt]) * rs[mt] * g4.z + bb4.z;
            o4.w = (acc[nt][mt][3] - mu[mt]) * rs[mt] * g4.w + bb4.w;
            *(float4*)(h + (i0 + m) * 128 + nb) = o4;
            uint2 u;
            u.x = pkbf(o4.x, o4.y); u.y = pkbf(o4.z, o4.w);
            *(uint2*)&act[swz(m, nb)] = u;
        }
    }
    __syncthreads();
    gemm32s(acc, act, Wp + 0 * 16384, wid, lane, lrow, q, true);     // mW0a -> P
    #pragma unroll
    for (int nt = 0; nt < 2; nt++) {
        int nb = colb + nt * 16 + q * 4;
        #pragma unroll
        for (int mt = 0; mt < 2; mt++) {
            int m = mt * 16 + lrow;
            uint2 u;
            u.x = pkbf(acc[nt][mt][0], acc[nt][mt][1]);
            u.y = pkbf(acc[nt][mt][2], acc[nt][mt][3]);
            *(uint2*)(Pd + (i0 + m) * 128 + nb) = u;
        }
    }
    gemm32s(acc, act, Wp + 1 * 16384, wid, lane, lrow, q, true);     // mW0b -> Q' (+mb0)
    #pragma unroll
    for (int nt = 0; nt < 2; nt++) {
        int nb = colb + nt * 16 + q * 4;
        float4 m4 = *(const float4*)&mb0[nb];
        #pragma unroll
        for (int mt = 0; mt < 2; mt++) {
            int m = mt * 16 + lrow;
            uint2 u;
            u.x = pkbf(acc[nt][mt][0] + m4.x, acc[nt][mt][1] + m4.y);
            u.y = pkbf(acc[nt][mt][2] + m4.z, acc[nt][mt][3] + m4.w);
            *(uint2*)(Qd + (i0 + m) * 128 + nb) = u;
        }
    }
}

__global__ __launch_bounds__(256) void k_out(const float* __restrict__ h, const float* __restrict__ W_out,
                                             const float* __restrict__ b_out, float* __restrict__ out) {
    int idx = blockIdx.x * 256 + threadIdx.x;   // < BN*9
    int row = idx / 9, o = idx - row * 9;
    const float4* h4 = (const float4*)(h + (size_t)row * 128);
    float s = b_out[o];
    #pragma unroll 8
    for (int k4 = 0; k4 < 32; k4++) {
        float4 v = h4[k4];
        int kb = k4 * 4;
        s += v.x * W_out[kb * 9 + o] + v.y * W_out[(kb + 1) * 9 + o]
           + v.z * W_out[(kb + 2) * 9 + o] + v.w * W_out[(kb + 3) * 9 + o];
    }
    out[idx] = s;
}

extern "C" void kernel_launch(void* const* d_in, const int* in_sizes, int n_in,
                              void* d_out, int out_size, void* d_ws, size_t ws_size,
                              hipStream_t stream) {
    const float* x    = (const float*)d_in[0];
    const int*   src  = (const int*)d_in[1];
    const float* W_in = (const float*)d_in[3];
    const float* b_in = (const float*)d_in[4];
    const float* pos  = (const float*)d_in[5];
    const float* mW0  = (const float*)d_in[6];
    const float* mb0  = (const float*)d_in[7];
    const float* mW1  = (const float*)d_in[8];
    const float* mb1  = (const float*)d_in[9];
    const float* mW2  = (const float*)d_in[10];
    const float* mb2  = (const float*)d_in[11];
    const float* mW3  = (const float*)d_in[12];
    const float* mb3  = (const float*)d_in[13];
    const float* nW0  = (const float*)d_in[14];
    const float* nb0  = (const float*)d_in[15];
    const float* nW1  = (const float*)d_in[16];
    const float* nb1  = (const float*)d_in[17];
    const float* nW2  = (const float*)d_in[18];
    const float* nb2  = (const float*)d_in[19];
    const float* nW3  = (const float*)d_in[20];
    const float* nb3  = (const float*)d_in[21];
    const float* ln_g = (const float*)d_in[22];
    const float* ln_b = (const float*)d_in[23];
    const float* W_out= (const float*)d_in[24];
    const float* b_out= (const float*)d_in[25];

    char* ws = (char*)d_ws;
    float*  h   = (float*)ws;                       // 21,233,664 B (also x_embed)
    float*  C2  = (float*)(ws + 21233664);          // 21,233,664 B
    bf16_t* SA  = (bf16_t*)(ws + 42467328);         // 10,616,832 B
    bf16_t* P   = (bf16_t*)(ws + 53084160);         // 10,616,832 B
    bf16_t* Q   = (bf16_t*)(ws + 63700992);         // 10,616,832 B (holds Q' = Q+mb0)
    bf16_t* Wp  = (bf16_t*)(ws + 74317824);         // 10 * 32,768 B (packed bf16)
    float*  bfix= (float*)(ws + 74645504);          // 512 B

    k_embed<<<20736, 256, 0, stream>>>(x, W_in, b_in, pos, h);

    // packed slots: 0=mW0a 1=mW0b 2=mW1 3=mW2 4=nW0a(h) 5=Ft 6=nW1 7=nW2 8=nW3 9=nW0b(x)
    PackArgs pa;
    pa.s[0] = mW0;  pa.s[1] = mW0 + 16384; pa.s[2] = mW1; pa.s[3] = mW2;
    pa.s[4] = nW0;  pa.s[5] = nW1;  pa.s[6] = nW2;  pa.s[7] = nW3;  pa.s[8] = nW0 + 16384;
    k_pack_all<<<576, 256, 0, stream>>>(pa, Wp);
    k_fuse<<<64, 256, 0, stream>>>(mW3, nW0, Wp + 5 * 16384);
    k_bias<<<1, 128, 0, stream>>>(nb0, mb3, nW0, bfix);

    k_simple3<<<972, 256, 0, stream>>>(h, Wp, bfix, mb0, C2, P, Q);   // C2, P0, Q'0

    for (int s = 0; s < 16; s++) {
        k_edge<<<dim3(7, 512), 512, 0, stream>>>(P, Q, src, Wp, mb1, mb2, SA);
        k_node<<<1296, 256, 0, stream>>>(h, SA, C2, Wp, nb1, nb2, nb3, ln_g, ln_b, mb0, P, Q);
    }
    k_out<<<1458, 256, 0, stream>>>(h, W_out, b_out, (float*)d_out);
}

// Round 9
// 2433.371 us; speedup vs baseline: 1.1932x; 1.1932x over previous
//
#include <hip/hip_runtime.h>
#include <hip/hip_bf16.h>

typedef __bf16 bf16_t;
typedef bf16_t bf16x8 __attribute__((ext_vector_type(8)));
typedef bf16_t bf16x4 __attribute__((ext_vector_type(4)));
typedef float  f32x4  __attribute__((ext_vector_type(4)));
typedef float  f32x16 __attribute__((ext_vector_type(16)));
typedef __hip_bfloat162 bf2;

#define NN   81
#define BB   512
#define BN   41472          // 512*81
#define EE   1620

__device__ __forceinline__ int swz(int r, int k) {
    return (r << 7) + ((((k >> 3) ^ (r & 7)) << 3) | (k & 7));
}

// 16x16x32 packed-weight offset (prep + node kernels)
__device__ __forceinline__ int wpack(int n, int k) {
    return ((n >> 6) << 13) + (((((k >> 5) << 2) + ((n >> 4) & 3))) << 9)
         + (((((k >> 3) & 3) << 4) + (n & 15)) << 3) + (k & 7);
}

// 32x32x16 packed-weight offset (edge kernel): tile (k>>4, n>>5) of 32n x 16k;
// lane l = ((k>>3)&1)*32 + (n&31) reads its A-fragment as one 16B load.
__device__ __forceinline__ int wpack32(int n, int k) {
    return ((((k >> 4) << 2) | (n >> 5)) << 9)
         + (((((k >> 3) & 1) << 5) | (n & 31)) << 3) + (k & 7);
}

// pack two f32 -> bf16x2, round-half-up: 2 adds + 1 v_perm
__device__ __forceinline__ unsigned pkbf(float lo, float hi) {
    unsigned a = __float_as_uint(lo) + 0x8000u;
    unsigned b = __float_as_uint(hi) + 0x8000u;
    return __builtin_amdgcn_perm(b, a, 0x07060302);
}

// truncating pack (1 v_perm) — intra-step activations only
__device__ __forceinline__ unsigned pkbf_t(float lo, float hi) {
    return __builtin_amdgcn_perm(__float_as_uint(hi), __float_as_uint(lo), 0x07060302);
}

// packed bf16x2 relu(p+q): 2 ops if HW has v_pk_add_bf16/v_pk_max, else lowers
__device__ __forceinline__ unsigned addrelu2(unsigned pd, unsigned qd) {
    unsigned zz = 0u;
    bf2 p = *(bf2*)&pd, q = *(bf2*)&qd, z = *(bf2*)&zz;
    bf2 r = __hmax2(__hadd2(p, q), z);
    return *(unsigned*)&r;
}

// ---------------- 16x16x32 GEMM pieces (prep + node) ----------------
__device__ __forceinline__ void stage_act_f32(bf16_t* act, const float* __restrict__ src, int tid) {
    for (int ch = tid; ch < 2048; ch += 256) {
        int r = ch >> 4, p = ch & 15;
        const float4 a = *(const float4*)(src + (size_t)r * 128 + p * 8);
        const float4 b = *(const float4*)(src + (size_t)r * 128 + p * 8 + 4);
        uint4 o;
        o.x = pkbf(a.x, a.y); o.y = pkbf(a.z, a.w);
        o.z = pkbf(b.x, b.y); o.w = pkbf(b.z, b.w);
        *(uint4*)&act[swz(r, p << 3)] = o;
    }
}

__device__ __forceinline__ void gemm128s(f32x4 (&acc)[4][4], const bf16_t* act,
                                         const bf16_t* __restrict__ Wp,
                                         int wm, int wn, int lane, int lrow, int q) {
    f32x4 z = {0.f, 0.f, 0.f, 0.f};
    #pragma unroll
    for (int i = 0; i < 4; i++)
        #pragma unroll
        for (int j = 0; j < 4; j++) acc[i][j] = z;
    const bf16_t* wbase = Wp + (wn << 13) + (lane << 3);
    #pragma unroll
    for (int k0 = 0; k0 < 128; k0 += 32) {
        bf16x8 af[4], wf[4];
        #pragma unroll
        for (int mt = 0; mt < 4; mt++)
            af[mt] = *(const bf16x8*)&act[swz(wm * 64 + mt * 16 + lrow, k0 + q * 8)];
        #pragma unroll
        for (int nt = 0; nt < 4; nt++)
            wf[nt] = *(const bf16x8*)(wbase + ((((k0 >> 5) << 2) + nt) << 9));
        #pragma unroll
        for (int nt = 0; nt < 4; nt++)
            #pragma unroll
            for (int mt = 0; mt < 4; mt++)
                acc[nt][mt] = __builtin_amdgcn_mfma_f32_16x16x32_bf16(wf[nt], af[mt], acc[nt][mt], 0, 0, 0);
    }
}

// ---------------- 32x32x16 GEMM (edge): wave tile 64m x 64n, bias-init ----------------
__device__ __forceinline__ void gemm32x32(f32x16 (&acc)[2][2], const bf16_t* act,
                                          const bf16_t* __restrict__ Wp,
                                          const float* __restrict__ bias,
                                          int wm, int wn, int lane) {
    int lm = lane & 31, h = lane >> 5;
    #pragma unroll
    for (int nt = 0; nt < 2; nt++)
        #pragma unroll
        for (int g = 0; g < 4; g++) {
            float4 b4 = *(const float4*)&bias[wn * 64 + nt * 32 + 8 * g + 4 * h];
            #pragma unroll
            for (int mt = 0; mt < 2; mt++) {
                acc[nt][mt][4 * g + 0] = b4.x; acc[nt][mt][4 * g + 1] = b4.y;
                acc[nt][mt][4 * g + 2] = b4.z; acc[nt][mt][4 * g + 3] = b4.w;
            }
        }
    const bf16_t* wl = Wp + ((wn * 2) << 9) + (lane << 3);
    #pragma unroll
    for (int kk = 0; kk < 8; kk++) {
        bf16x8 af[2], wf[2];
        #pragma unroll
        for (int mt = 0; mt < 2; mt++)
            af[mt] = *(const bf16x8*)&act[swz(wm * 64 + mt * 32 + lm, kk * 16 + h * 8)];
        #pragma unroll
        for (int nt = 0; nt < 2; nt++)
            wf[nt] = *(const bf16x8*)(wl + (((kk << 2) + nt) << 9));
        #pragma unroll
        for (int nt = 0; nt < 2; nt++)
            #pragma unroll
            for (int mt = 0; mt < 2; mt++)
                acc[nt][mt] = __builtin_amdgcn_mfma_f32_32x32x16_bf16(wf[nt], af[mt], acc[nt][mt], 0, 0, 0);
    }
}

// relu writeback for 32x32 D-layout: n = wn*64+nt*32+8g+4h+(0..3), m = wm*64+mt*32+lm
__device__ __forceinline__ void wb32x32(bf16_t* act, f32x16 (&acc)[2][2], int wm, int wn, int lane) {
    int lm = lane & 31, h = lane >> 5;
    #pragma unroll
    for (int nt = 0; nt < 2; nt++)
        #pragma unroll
        for (int g = 0; g < 4; g++) {
            int nb = wn * 64 + nt * 32 + 8 * g + 4 * h;
            #pragma unroll
            for (int mt = 0; mt < 2; mt++) {
                int m = wm * 64 + mt * 32 + lm;
                uint2 u;
                u.x = pkbf_t(fmaxf(acc[nt][mt][4 * g + 0], 0.f), fmaxf(acc[nt][mt][4 * g + 1], 0.f));
                u.y = pkbf_t(fmaxf(acc[nt][mt][4 * g + 2], 0.f), fmaxf(acc[nt][mt][4 * g + 3], 0.f));
                *(uint2*)&act[swz(m, nb)] = u;
            }
        }
}

// ---------------- node-kernel GEMM: wave tile 32(M) x 32(N) ----------------
__device__ __forceinline__ void gemm32s(f32x4 (&acc)[2][2], const bf16_t* act,
                                        const bf16_t* __restrict__ Wp,
                                        int wid, int lane, int lrow, int q, bool zero) {
    if (zero) {
        f32x4 z = {0.f, 0.f, 0.f, 0.f};
        acc[0][0] = z; acc[0][1] = z; acc[1][0] = z; acc[1][1] = z;
    }
    int wn = wid >> 1, ntb = (wid & 1) << 1;
    const bf16_t* wbase = Wp + (wn << 13) + (lane << 3);
    #pragma unroll
    for (int k0 = 0; k0 < 128; k0 += 32) {
        bf16x8 af[2], wf[2];
        af[0] = *(const bf16x8*)&act[swz(lrow, k0 + q * 8)];
        af[1] = *(const bf16x8*)&act[swz(16 + lrow, k0 + q * 8)];
        wf[0] = *(const bf16x8*)(wbase + ((((k0 >> 5) << 2) + ntb) << 9));
        wf[1] = *(const bf16x8*)(wbase + ((((k0 >> 5) << 2) + ntb + 1) << 9));
        #pragma unroll
        for (int nt = 0; nt < 2; nt++)
            #pragma unroll
            for (int mt = 0; mt < 2; mt++)
                acc[nt][mt] = __builtin_amdgcn_mfma_f32_16x16x32_bf16(wf[nt], af[mt], acc[nt][mt], 0, 0, 0);
    }
}

__device__ __forceinline__ void wb32(bf16_t* act, f32x4 (&acc)[2][2], const float* __restrict__ bias,
                                     int colb, int lrow, int q) {
    #pragma unroll
    for (int nt = 0; nt < 2; nt++) {
        int nb = colb + nt * 16 + q * 4;
        float4 b4 = *(const float4*)&bias[nb];
        #pragma unroll
        for (int mt = 0; mt < 2; mt++) {
            int m = mt * 16 + lrow;
            uint2 u;
            u.x = pkbf_t(fmaxf(acc[nt][mt][0] + b4.x, 0.f), fmaxf(acc[nt][mt][1] + b4.y, 0.f));
            u.y = pkbf_t(fmaxf(acc[nt][mt][2] + b4.z, 0.f), fmaxf(acc[nt][mt][3] + b4.w, 0.f));
            *(uint2*)&act[swz(m, nb)] = u;
        }
    }
}

// ---------------- prep kernels ----------------

__global__ __launch_bounds__(256) void k_embed(const float* __restrict__ x, const float* __restrict__ W_in,
                                               const float* __restrict__ b_in, const float* __restrict__ pos,
                                               float* __restrict__ h) {
    int idx = blockIdx.x * 256 + threadIdx.x;   // < BN*128
    int row = idx >> 7, col = idx & 127;
    int n = row % NN;
    const float* xr = x + (size_t)row * 10;
    float s = b_in[col] + pos[n * 128 + col];
    #pragma unroll
    for (int k = 0; k < 10; k++) s += xr[k] * W_in[k * 128 + col];
    h[idx] = s;
}

struct PackArgs { const float* s[9]; };

__global__ __launch_bounds__(256) void k_pack_all(PackArgs pa, bf16_t* __restrict__ dst) {
    const int slot[9] = {0, 1, 2, 3, 4, 6, 7, 8, 9};
    int idx = blockIdx.x * 256 + threadIdx.x;   // < 9*16384
    int w = idx >> 14, r = idx & 16383;
    int n = r >> 7, k = r & 127;
    int po = (w == 2 || w == 3) ? wpack32(n, k) : wpack(n, k);   // edge weights use 32x32 layout
    dst[slot[w] * 16384 + po] = (bf16_t)pa.s[w][k * 128 + n];
}

__global__ __launch_bounds__(256) void k_fuse(const float* __restrict__ mW3, const float* __restrict__ nW0,
                                              bf16_t* __restrict__ Ft) {
    int idx = blockIdx.x * 256 + threadIdx.x;   // < 16384
    int n = idx >> 7, k = idx & 127;
    float s = 0.f;
    for (int j = 0; j < 128; j++) s += mW3[k * 128 + j] * nW0[(256 + j) * 128 + n];
    Ft[wpack(n, k)] = (bf16_t)s;
}

__global__ __launch_bounds__(128) void k_bias(const float* __restrict__ nb0, const float* __restrict__ mb3,
                                              const float* __restrict__ nW0, float* __restrict__ bfix) {
    int n = threadIdx.x;
    float s = 0.f;
    for (int j = 0; j < 128; j++) s += mb3[j] * nW0[(256 + j) * 128 + n];
    bfix[n] = nb0[n] + 20.f * s;
}

// one launch does C2 (f32, bias=bfix), P (bf16), Q' (bf16, bias=mb0)
__global__ __launch_bounds__(256, 2) void k_simple3(const float* __restrict__ in,
                                                    const bf16_t* __restrict__ Wp,
                                                    const float* __restrict__ bfix,
                                                    const float* __restrict__ mb0,
                                                    float* __restrict__ C2,
                                                    bf16_t* __restrict__ Pd,
                                                    bf16_t* __restrict__ Qd) {
    __shared__ __align__(16) bf16_t act[16384];
    int tid = threadIdx.x;
    int sel = blockIdx.x / 324, blk = blockIdx.x - sel * 324;
    size_t i0 = (size_t)blk * 128;
    int lane = tid & 63, wid = tid >> 6;
    int wm = wid >> 1, wn = wid & 1, lrow = lane & 15, q = lane >> 4;

    stage_act_f32(act, in + i0 * 128, tid);
    __syncthreads();
    const bf16_t* W = Wp + (sel == 0 ? 9 * 16384 : (sel == 1 ? 0 : 16384));
    f32x4 acc[4][4];
    gemm128s(acc, act, W, wm, wn, lane, lrow, q);
    #pragma unroll
    for (int nt = 0; nt < 4; nt++) {
        int nb = wn * 64 + nt * 16 + q * 4;
        float4 b4 = (sel == 0) ? *(const float4*)&bfix[nb]
                  : (sel == 2) ? *(const float4*)&mb0[nb]
                               : make_float4(0.f, 0.f, 0.f, 0.f);
        #pragma unroll
        for (int mt = 0; mt < 4; mt++) {
            int m = wm * 64 + mt * 16 + lrow;
            float v0 = acc[nt][mt][0] + b4.x, v1 = acc[nt][mt][1] + b4.y;
            float v2 = acc[nt][mt][2] + b4.z, v3 = acc[nt][mt][3] + b4.w;
            if (sel == 0) {
                float4 o; o.x = v0; o.y = v1; o.z = v2; o.w = v3;
                *(float4*)(C2 + (i0 + m) * 128 + nb) = o;
            } else {
                uint2 u; u.x = pkbf(v0, v1); u.y = pkbf(v2, v3);
                bf16_t* dst = (sel == 1) ? Pd : Qd;
                *(uint2*)(dst + (i0 + m) * 128 + nb) = u;
            }
        }
    }
}

// ---------------- edge kernel: r7 shape, 32x32x16 MFMA, packed-bf16 staging ----------------
__global__ __launch_bounds__(256, 3) void k_edge(const bf16_t* __restrict__ P, const bf16_t* __restrict__ Q,
                                                 const int* __restrict__ src, const bf16_t* __restrict__ Wp,
                                                 const float* __restrict__ mb1, const float* __restrict__ mb2,
                                                 bf16_t* __restrict__ SA) {
    __shared__ __align__(16) bf16_t act[16384];
    int tid = threadIdx.x;
    int g = blockIdx.x, b = blockIdx.y;
    int e0 = g * 120, n0 = g * 6;
    int nreal = (e0 + 120 <= EE) ? 120 : (EE - e0);   // 120 or 60
    int lane = tid & 63, wid = tid >> 6;
    int wm = wid >> 1, wn = wid & 1;

    // layer-0: act0 = relu(P[src] + Q'[dst]) (Q' has +mb0 folded), packed bf16 ops
    for (int ch = tid; ch < 2048; ch += 256) {
        int r = ch >> 4, p = ch & 15;
        uint4 o;
        if (r < nreal) {
            int e = e0 + r;
            int sn = src[e];
            int dn = n0 + r / 20;
            uint4 pv = *(const uint4*)(P + (((size_t)b * NN + sn) << 7) + (p << 3));
            uint4 qv = *(const uint4*)(Q + (((size_t)b * NN + dn) << 7) + (p << 3));
            o.x = addrelu2(pv.x, qv.x);
            o.y = addrelu2(pv.y, qv.y);
            o.z = addrelu2(pv.z, qv.z);
            o.w = addrelu2(pv.w, qv.w);
        } else {
            o.x = 0u; o.y = 0u; o.z = 0u; o.w = 0u;
        }
        *(uint4*)&act[swz(r, p << 3)] = o;
    }
    __syncthreads();

    f32x16 acc[2][2];
    gemm32x32(acc, act, Wp + 2 * 16384, mb1, wm, wn, lane);   // act0 @ mW1 + mb1
    __syncthreads();
    wb32x32(act, acc, wm, wn, lane);                          // act1 = relu
    __syncthreads();
    gemm32x32(acc, act, Wp + 3 * 16384, mb2, wm, wn, lane);   // act1 @ mW2 + mb2
    __syncthreads();
    wb32x32(act, acc, wm, wn, lane);                          // act2 = relu
    __syncthreads();

    // SA[b][n0+j][c] = sum of act2 over the node's 20 edges (2-thread split)
    if (tid < 192) {
        int j = tid >> 5;              // node 0..5
        int sub = tid & 31;
        int rr = sub >> 1;             // 8-feature chunk
        int half = sub & 1;
        int nodes = nreal / 20;
        if (j < nodes) {
            float s0 = 0.f, s1 = 0.f, s2 = 0.f, s3 = 0.f, s4 = 0.f, s5 = 0.f, s6 = 0.f, s7 = 0.f;
            #pragma unroll
            for (int i = 0; i < 10; i++) {
                int m = 20 * j + half * 10 + i;
                bf16x8 v = *(const bf16x8*)&act[swz(m, rr << 3)];
                s0 += (float)v[0]; s1 += (float)v[1]; s2 += (float)v[2]; s3 += (float)v[3];
                s4 += (float)v[4]; s5 += (float)v[5]; s6 += (float)v[6]; s7 += (float)v[7];
            }
            s0 += __shfl_xor(s0, 1); s1 += __shfl_xor(s1, 1);
            s2 += __shfl_xor(s2, 1); s3 += __shfl_xor(s3, 1);
            s4 += __shfl_xor(s4, 1); s5 += __shfl_xor(s5, 1);
            s6 += __shfl_xor(s6, 1); s7 += __shfl_xor(s7, 1);
            if (half == 0) {
                uint4 o;
                o.x = pkbf(s0, s1); o.y = pkbf(s2, s3);
                o.z = pkbf(s4, s5); o.w = pkbf(s6, s7);
                *(uint4*)(SA + (((size_t)b * NN + n0 + j) << 7) + (rr << 3)) = o;
            }
        }
    }
}

// ---------------- node kernel: M=32, 4 waves x N=32, separate SA buffer ----------------
__global__ __launch_bounds__(256, 4) void k_node(float* __restrict__ h, const bf16_t* __restrict__ SA,
                                                 const float* __restrict__ C2, const bf16_t* __restrict__ Wp,
                                                 const float* __restrict__ nb1, const float* __restrict__ nb2,
                                                 const float* __restrict__ nb3, const float* __restrict__ ln_g,
                                                 const float* __restrict__ ln_b, const float* __restrict__ mb0,
                                                 bf16_t* __restrict__ Pd, bf16_t* __restrict__ Qd) {
    __shared__ __align__(16) bf16_t act[4096];   // 32 rows x 128
    __shared__ __align__(16) bf16_t sab[4096];   // staged SA
    __shared__ float st[256];                    // 32 rows x 4 waves x {s1,s2}
    int tid = threadIdx.x;
    size_t i0 = (size_t)blockIdx.x * 32;
    int lane = tid & 63, wid = tid >> 6;
    int lrow = lane & 15, q = lane >> 4;
    int colb = wid * 32;

    // stage h (f32->bf16, packed) and SA (raw copy) in one pass
    for (int ch = tid; ch < 1024; ch += 256) {
        if (ch < 512) {
            int r = ch >> 4, p = ch & 15;
            const float4 a = *(const float4*)(h + (i0 + r) * 128 + (p << 3));
            const float4 c = *(const float4*)(h + (i0 + r) * 128 + (p << 3) + 4);
            uint4 o;
            o.x = pkbf(a.x, a.y); o.y = pkbf(a.z, a.w);
            o.z = pkbf(c.x, c.y); o.w = pkbf(c.z, c.w);
            *(uint4*)&act[swz(r, p << 3)] = o;
        } else {
            int r = (ch - 512) >> 4, p = ch & 15;
            *(uint4*)&sab[swz(r, p << 3)] = *(const uint4*)(SA + (i0 + r) * 128 + (p << 3));
        }
    }
    __syncthreads();
    f32x4 acc[2][2];
    gemm32s(acc, act, Wp + 4 * 16384, wid, lane, lrow, q, true);     // h @ nW0a
    gemm32s(acc, sab, Wp + 5 * 16384, wid, lane, lrow, q, false);    // + SA @ Ft
    __syncthreads();
    // u0 = relu(acc + C2)
    #pragma unroll
    for (int nt = 0; nt < 2; nt++) {
        int nb = colb + nt * 16 + q * 4;
        #pragma unroll
        for (int mt = 0; mt < 2; mt++) {
            int m = mt * 16 + lrow;
            float4 c4 = *(const float4*)(C2 + (i0 + m) * 128 + nb);
            uint2 u;
            u.x = pkbf_t(fmaxf(acc[nt][mt][0] + c4.x, 0.f), fmaxf(acc[nt][mt][1] + c4.y, 0.f));
            u.y = pkbf_t(fmaxf(acc[nt][mt][2] + c4.z, 0.f), fmaxf(acc[nt][mt][3] + c4.w, 0.f));
            *(uint2*)&act[swz(m, nb)] = u;
        }
    }
    __syncthreads();
    gemm32s(acc, act, Wp + 6 * 16384, wid, lane, lrow, q, true);     // nW1
    __syncthreads();
    wb32(act, acc, nb1, colb, lrow, q);
    __syncthreads();
    gemm32s(acc, act, Wp + 7 * 16384, wid, lane, lrow, q, true);     // nW2
    __syncthreads();
    wb32(act, acc, nb2, colb, lrow, q);
    __syncthreads();
    gemm32s(acc, act, Wp + 8 * 16384, wid, lane, lrow, q, true);     // nW3

    // residual v = acc + nb3 + h, LN stats
    float s1[2] = {0.f, 0.f}, s2[2] = {0.f, 0.f};
    #pragma unroll
    for (int nt = 0; nt < 2; nt++) {
        int nb = colb + nt * 16 + q * 4;
        float4 b4 = *(const float4*)&nb3[nb];
        #pragma unroll
        for (int mt = 0; mt < 2; mt++) {
            int m = mt * 16 + lrow;
            float4 h4 = *(const float4*)(h + (i0 + m) * 128 + nb);
            float v0 = acc[nt][mt][0] + b4.x + h4.x;
            float v1 = acc[nt][mt][1] + b4.y + h4.y;
            float v2 = acc[nt][mt][2] + b4.z + h4.z;
            float v3 = acc[nt][mt][3] + b4.w + h4.w;
            acc[nt][mt][0] = v0; acc[nt][mt][1] = v1;
            acc[nt][mt][2] = v2; acc[nt][mt][3] = v3;
            s1[mt] += v0 + v1 + v2 + v3;
            s2[mt] += v0 * v0 + v1 * v1 + v2 * v2 + v3 * v3;
        }
    }
    #pragma unroll
    for (int mt = 0; mt < 2; mt++) {
        float a = s1[mt], c = s2[mt];
        a += __shfl_xor(a, 16); c += __shfl_xor(c, 16);
        a += __shfl_xor(a, 32); c += __shfl_xor(c, 32);
        s1[mt] = a; s2[mt] = c;
    }
    if (q == 0) {
        #pragma unroll
        for (int mt = 0; mt < 2; mt++) {
            st[(mt * 16 + lrow) * 8 + wid * 2 + 0] = s1[mt];
            st[(mt * 16 + lrow) * 8 + wid * 2 + 1] = s2[mt];
        }
    }
    __syncthreads();
    float mu[2], rs[2];
    #pragma unroll
    for (int mt = 0; mt < 2; mt++) {
        int m = mt * 16 + lrow;
        float a = st[m * 8 + 0] + st[m * 8 + 2] + st[m * 8 + 4] + st[m * 8 + 6];
        float c = st[m * 8 + 1] + st[m * 8 + 3] + st[m * 8 + 5] + st[m * 8 + 7];
        a *= (1.f / 128.f); c *= (1.f / 128.f);
        mu[mt] = a;
        rs[mt] = rsqrtf(c - a * a + 1e-5f);
    }
    // LN apply -> h (f32) and act (bf16 for P/Q gemms)
    #pragma unroll
    for (int nt = 0; nt < 2; nt++) {
        int nb = colb + nt * 16 + q * 4;
        float4 g4 = *(const float4*)&ln_g[nb];
        float4 bb4 = *(const float4*)&ln_b[nb];
        #pragma unroll
        for (int mt = 0; mt < 2; mt++) {
            int m = mt * 16 + lrow;
            float4 o4;
            o4.x = (acc[nt][mt][0] - mu[mt]) * rs[mt] * g4.x + bb4.x;
            o4.y = (acc[nt][mt][1] - mu[mt]) * rs[mt] * g4.y + bb4.y;
            o4.z = (acc[nt][mt][2] - mu[mt]) * rs[mt] * g4.z + bb4.z;
            o4.w = (acc[nt][mt][3] - mu[mt]) * rs[mt] * g4.w + bb4.w;
            *(float4*)(h + (i0 + m) * 128 + nb) = o4;
            uint2 u;
            u.x = pkbf(o4.x, o4.y); u.y = pkbf(o4.z, o4.w);
            *(uint2*)&act[swz(m, nb)] = u;
        }
    }
    __syncthreads();
    gemm32s(acc, act, Wp + 0 * 16384, wid, lane, lrow, q, true);     // mW0a -> P
    #pragma unroll
    for (int nt = 0; nt < 2; nt++) {
        int nb = colb + nt * 16 + q * 4;
        #pragma unroll
        for (int mt = 0; mt < 2; mt++) {
            int m = mt * 16 + lrow;
            uint2 u;
            u.x = pkbf(acc[nt][mt][0], acc[nt][mt][1]);
            u.y = pkbf(acc[nt][mt][2], acc[nt][mt][3]);
            *(uint2*)(Pd + (i0 + m) * 128 + nb) = u;
        }
    }
    gemm32s(acc, act, Wp + 1 * 16384, wid, lane, lrow, q, true);     // mW0b -> Q' (+mb0)
    #pragma unroll
    for (int nt = 0; nt < 2; nt++) {
        int nb = colb + nt * 16 + q * 4;
        float4 m4 = *(const float4*)&mb0[nb];
        #pragma unroll
        for (int mt = 0; mt < 2; mt++) {
            int m = mt * 16 + lrow;
            uint2 u;
            u.x = pkbf(acc[nt][mt][0] + m4.x, acc[nt][mt][1] + m4.y);
            u.y = pkbf(acc[nt][mt][2] + m4.z, acc[nt][mt][3] + m4.w);
            *(uint2*)(Qd + (i0 + m) * 128 + nb) = u;
        }
    }
}

__global__ __launch_bounds__(256) void k_out(const float* __restrict__ h, const float* __restrict__ W_out,
                                             const float* __restrict__ b_out, float* __restrict__ out) {
    int idx = blockIdx.x * 256 + threadIdx.x;   // < BN*9
    int row = idx / 9, o = idx - row * 9;
    const float4* h4 = (const float4*)(h + (size_t)row * 128);
    float s = b_out[o];
    #pragma unroll 8
    for (int k4 = 0; k4 < 32; k4++) {
        float4 v = h4[k4];
        int kb = k4 * 4;
        s += v.x * W_out[kb * 9 + o] + v.y * W_out[(kb + 1) * 9 + o]
           + v.z * W_out[(kb + 2) * 9 + o] + v.w * W_out[(kb + 3) * 9 + o];
    }
    out[idx] = s;
}

extern "C" void kernel_launch(void* const* d_in, const int* in_sizes, int n_in,
                              void* d_out, int out_size, void* d_ws, size_t ws_size,
                              hipStream_t stream) {
    const float* x    = (const float*)d_in[0];
    const int*   src  = (const int*)d_in[1];
    const float* W_in = (const float*)d_in[3];
    const float* b_in = (const float*)d_in[4];
    const float* pos  = (const float*)d_in[5];
    const float* mW0  = (const float*)d_in[6];
    const float* mb0  = (const float*)d_in[7];
    const float* mW1  = (const float*)d_in[8];
    const float* mb1  = (const float*)d_in[9];
    const float* mW2  = (const float*)d_in[10];
    const float* mb2  = (const float*)d_in[11];
    const float* mW3  = (const float*)d_in[12];
    const float* mb3  = (const float*)d_in[13];
    const float* nW0  = (const float*)d_in[14];
    const float* nb0  = (const float*)d_in[15];
    const float* nW1  = (const float*)d_in[16];
    const float* nb1  = (const float*)d_in[17];
    const float* nW2  = (const float*)d_in[18];
    const float* nb2  = (const float*)d_in[19];
    const float* nW3  = (const float*)d_in[20];
    const float* nb3  = (const float*)d_in[21];
    const float* ln_g = (const float*)d_in[22];
    const float* ln_b = (const float*)d_in[23];
    const float* W_out= (const float*)d_in[24];
    const float* b_out= (const float*)d_in[25];

    char* ws = (char*)d_ws;
    float*  h   = (float*)ws;                       // 21,233,664 B (also x_embed)
    float*  C2  = (float*)(ws + 21233664);          // 21,233,664 B
    bf16_t* SA  = (bf16_t*)(ws + 42467328);         // 10,616,832 B
    bf16_t* P   = (bf16_t*)(ws + 53084160);         // 10,616,832 B
    bf16_t* Q   = (bf16_t*)(ws + 63700992);         // 10,616,832 B (holds Q' = Q+mb0)
    bf16_t* Wp  = (bf16_t*)(ws + 74317824);         // 10 * 32,768 B (packed bf16)
    float*  bfix= (float*)(ws + 74645504);          // 512 B

    k_embed<<<20736, 256, 0, stream>>>(x, W_in, b_in, pos, h);

    // packed slots: 0=mW0a 1=mW0b 2=mW1(32x32) 3=mW2(32x32) 4=nW0a(h) 5=Ft 6=nW1 7=nW2 8=nW3 9=nW0b(x)
    PackArgs pa;
    pa.s[0] = mW0;  pa.s[1] = mW0 + 16384; pa.s[2] = mW1; pa.s[3] = mW2;
    pa.s[4] = nW0;  pa.s[5] = nW1;  pa.s[6] = nW2;  pa.s[7] = nW3;  pa.s[8] = nW0 + 16384;
    k_pack_all<<<576, 256, 0, stream>>>(pa, Wp);
    k_fuse<<<64, 256, 0, stream>>>(mW3, nW0, Wp + 5 * 16384);
    k_bias<<<1, 128, 0, stream>>>(nb0, mb3, nW0, bfix);

    k_simple3<<<972, 256, 0, stream>>>(h, Wp, bfix, mb0, C2, P, Q);   // C2, P0, Q'0

    for (int s = 0; s < 16; s++) {
        k_edge<<<dim3(14, 512), 256, 0, stream>>>(P, Q, src, Wp, mb1, mb2, SA);
        k_node<<<1296, 256, 0, stream>>>(h, SA, C2, Wp, nb1, nb2, nb3, ln_g, ln_b, mb0, P, Q);
    }
    k_out<<<1458, 256, 0, stream>>>(h, W_out, b_out, (float*)d_out);
}

// Round 10
// 2421.816 us; speedup vs baseline: 1.1988x; 1.0048x over previous
//
#include <hip/hip_runtime.h>
#include <hip/hip_bf16.h>

typedef __bf16 bf16_t;
typedef bf16_t bf16x8 __attribute__((ext_vector_type(8)));
typedef bf16_t bf16x4 __attribute__((ext_vector_type(4)));
typedef float  f32x4  __attribute__((ext_vector_type(4)));
typedef float  f32x16 __attribute__((ext_vector_type(16)));
typedef __hip_bfloat162 bf2;

#define NN   81
#define BB   512
#define BN   41472          // 512*81
#define EE   1620

__device__ __forceinline__ int swz(int r, int k) {
    return (r << 7) + ((((k >> 3) ^ (r & 7)) << 3) | (k & 7));
}

// 16x16x32 packed-weight offset (prep + node kernels)
__device__ __forceinline__ int wpack(int n, int k) {
    return ((n >> 6) << 13) + (((((k >> 5) << 2) + ((n >> 4) & 3))) << 9)
         + (((((k >> 3) & 3) << 4) + (n & 15)) << 3) + (k & 7);
}

// 32x32x16 packed-weight offset (edge kernel)
__device__ __forceinline__ int wpack32(int n, int k) {
    return ((((k >> 4) << 2) | (n >> 5)) << 9)
         + (((((k >> 3) & 1) << 5) | (n & 31)) << 3) + (k & 7);
}

// pack two f32 -> bf16x2, round-half-up: 2 adds + 1 v_perm
__device__ __forceinline__ unsigned pkbf(float lo, float hi) {
    unsigned a = __float_as_uint(lo) + 0x8000u;
    unsigned b = __float_as_uint(hi) + 0x8000u;
    return __builtin_amdgcn_perm(b, a, 0x07060302);
}

// truncating pack (1 v_perm) — intra-step activations only
__device__ __forceinline__ unsigned pkbf_t(float lo, float hi) {
    return __builtin_amdgcn_perm(__float_as_uint(hi), __float_as_uint(lo), 0x07060302);
}

// packed bf16x2 relu(p+q)
__device__ __forceinline__ unsigned addrelu2(unsigned pd, unsigned qd) {
    unsigned zz = 0u;
    bf2 p = *(bf2*)&pd, q = *(bf2*)&qd, z = *(bf2*)&zz;
    bf2 r = __hmax2(__hadd2(p, q), z);
    return *(unsigned*)&r;
}

// ---------------- 16x16x32 GEMM pieces (prep + node) ----------------
__device__ __forceinline__ void stage_act_f32(bf16_t* act, const float* __restrict__ src, int tid) {
    for (int ch = tid; ch < 2048; ch += 256) {
        int r = ch >> 4, p = ch & 15;
        const float4 a = *(const float4*)(src + (size_t)r * 128 + p * 8);
        const float4 b = *(const float4*)(src + (size_t)r * 128 + p * 8 + 4);
        uint4 o;
        o.x = pkbf(a.x, a.y); o.y = pkbf(a.z, a.w);
        o.z = pkbf(b.x, b.y); o.w = pkbf(b.z, b.w);
        *(uint4*)&act[swz(r, p << 3)] = o;
    }
}

__device__ __forceinline__ void gemm128s(f32x4 (&acc)[4][4], const bf16_t* act,
                                         const bf16_t* __restrict__ Wp,
                                         int wm, int wn, int lane, int lrow, int q) {
    f32x4 z = {0.f, 0.f, 0.f, 0.f};
    #pragma unroll
    for (int i = 0; i < 4; i++)
        #pragma unroll
        for (int j = 0; j < 4; j++) acc[i][j] = z;
    const bf16_t* wbase = Wp + (wn << 13) + (lane << 3);
    #pragma unroll
    for (int k0 = 0; k0 < 128; k0 += 32) {
        bf16x8 af[4], wf[4];
        #pragma unroll
        for (int mt = 0; mt < 4; mt++)
            af[mt] = *(const bf16x8*)&act[swz(wm * 64 + mt * 16 + lrow, k0 + q * 8)];
        #pragma unroll
        for (int nt = 0; nt < 4; nt++)
            wf[nt] = *(const bf16x8*)(wbase + ((((k0 >> 5) << 2) + nt) << 9));
        #pragma unroll
        for (int nt = 0; nt < 4; nt++)
            #pragma unroll
            for (int mt = 0; mt < 4; mt++)
                acc[nt][mt] = __builtin_amdgcn_mfma_f32_16x16x32_bf16(wf[nt], af[mt], acc[nt][mt], 0, 0, 0);
    }
}

// ---------------- 32x32x16 GEMM (edge): wave tile 64m x 64n, bias-init ----------------
__device__ __forceinline__ void gemm32x32(f32x16 (&acc)[2][2], const bf16_t* act,
                                          const bf16_t* __restrict__ Wp,
                                          const float* __restrict__ bias,
                                          int wm, int wn, int lane) {
    int lm = lane & 31, h = lane >> 5;
    #pragma unroll
    for (int nt = 0; nt < 2; nt++)
        #pragma unroll
        for (int g = 0; g < 4; g++) {
            float4 b4 = *(const float4*)&bias[wn * 64 + nt * 32 + 8 * g + 4 * h];
            #pragma unroll
            for (int mt = 0; mt < 2; mt++) {
                acc[nt][mt][4 * g + 0] = b4.x; acc[nt][mt][4 * g + 1] = b4.y;
                acc[nt][mt][4 * g + 2] = b4.z; acc[nt][mt][4 * g + 3] = b4.w;
            }
        }
    const bf16_t* wl = Wp + ((wn * 2) << 9) + (lane << 3);
    #pragma unroll
    for (int kk = 0; kk < 8; kk++) {
        bf16x8 af[2], wf[2];
        #pragma unroll
        for (int mt = 0; mt < 2; mt++)
            af[mt] = *(const bf16x8*)&act[swz(wm * 64 + mt * 32 + lm, kk * 16 + h * 8)];
        #pragma unroll
        for (int nt = 0; nt < 2; nt++)
            wf[nt] = *(const bf16x8*)(wl + (((kk << 2) + nt) << 9));
        #pragma unroll
        for (int nt = 0; nt < 2; nt++)
            #pragma unroll
            for (int mt = 0; mt < 2; mt++)
                acc[nt][mt] = __builtin_amdgcn_mfma_f32_32x32x16_bf16(wf[nt], af[mt], acc[nt][mt], 0, 0, 0);
    }
}

// relu writeback for 32x32 D-layout: n = wn*64+nt*32+8g+4h+(0..3), m = wm*64+mt*32+lm
__device__ __forceinline__ void wb32x32(bf16_t* act, f32x16 (&acc)[2][2], int wm, int wn, int lane) {
    int lm = lane & 31, h = lane >> 5;
    #pragma unroll
    for (int nt = 0; nt < 2; nt++)
        #pragma unroll
        for (int g = 0; g < 4; g++) {
            int nb = wn * 64 + nt * 32 + 8 * g + 4 * h;
            #pragma unroll
            for (int mt = 0; mt < 2; mt++) {
                int m = wm * 64 + mt * 32 + lm;
                uint2 u;
                u.x = pkbf_t(fmaxf(acc[nt][mt][4 * g + 0], 0.f), fmaxf(acc[nt][mt][4 * g + 1], 0.f));
                u.y = pkbf_t(fmaxf(acc[nt][mt][4 * g + 2], 0.f), fmaxf(acc[nt][mt][4 * g + 3], 0.f));
                *(uint2*)&act[swz(m, nb)] = u;
            }
        }
}

// ---------------- node-kernel GEMM: wave tile 32(M) x 32(N) ----------------
__device__ __forceinline__ void gemm32s(f32x4 (&acc)[2][2], const bf16_t* act,
                                        const bf16_t* __restrict__ Wp,
                                        int wid, int lane, int lrow, int q, bool zero) {
    if (zero) {
        f32x4 z = {0.f, 0.f, 0.f, 0.f};
        acc[0][0] = z; acc[0][1] = z; acc[1][0] = z; acc[1][1] = z;
    }
    int wn = wid >> 1, ntb = (wid & 1) << 1;
    const bf16_t* wbase = Wp + (wn << 13) + (lane << 3);
    #pragma unroll
    for (int k0 = 0; k0 < 128; k0 += 32) {
        bf16x8 af[2], wf[2];
        af[0] = *(const bf16x8*)&act[swz(lrow, k0 + q * 8)];
        af[1] = *(const bf16x8*)&act[swz(16 + lrow, k0 + q * 8)];
        wf[0] = *(const bf16x8*)(wbase + ((((k0 >> 5) << 2) + ntb) << 9));
        wf[1] = *(const bf16x8*)(wbase + ((((k0 >> 5) << 2) + ntb + 1) << 9));
        #pragma unroll
        for (int nt = 0; nt < 2; nt++)
            #pragma unroll
            for (int mt = 0; mt < 2; mt++)
                acc[nt][mt] = __builtin_amdgcn_mfma_f32_16x16x32_bf16(wf[nt], af[mt], acc[nt][mt], 0, 0, 0);
    }
}

__device__ __forceinline__ void wb32(bf16_t* act, f32x4 (&acc)[2][2], const float* __restrict__ bias,
                                     int colb, int lrow, int q) {
    #pragma unroll
    for (int nt = 0; nt < 2; nt++) {
        int nb = colb + nt * 16 + q * 4;
        float4 b4 = *(const float4*)&bias[nb];
        #pragma unroll
        for (int mt = 0; mt < 2; mt++) {
            int m = mt * 16 + lrow;
            uint2 u;
            u.x = pkbf_t(fmaxf(acc[nt][mt][0] + b4.x, 0.f), fmaxf(acc[nt][mt][1] + b4.y, 0.f));
            u.y = pkbf_t(fmaxf(acc[nt][mt][2] + b4.z, 0.f), fmaxf(acc[nt][mt][3] + b4.w, 0.f));
            *(uint2*)&act[swz(m, nb)] = u;
        }
    }
}

// ---------------- prep kernels ----------------

__global__ __launch_bounds__(256) void k_embed(const float* __restrict__ x, const float* __restrict__ W_in,
                                               const float* __restrict__ b_in, const float* __restrict__ pos,
                                               float* __restrict__ h) {
    int idx = blockIdx.x * 256 + threadIdx.x;   // < BN*128
    int row = idx >> 7, col = idx & 127;
    int n = row % NN;
    const float* xr = x + (size_t)row * 10;
    float s = b_in[col] + pos[n * 128 + col];
    #pragma unroll
    for (int k = 0; k < 10; k++) s += xr[k] * W_in[k * 128 + col];
    h[idx] = s;
}

struct PackArgs { const float* s[9]; };

__global__ __launch_bounds__(256) void k_pack_all(PackArgs pa, bf16_t* __restrict__ dst) {
    const int slot[9] = {0, 1, 2, 3, 4, 6, 7, 8, 9};
    int idx = blockIdx.x * 256 + threadIdx.x;   // < 9*16384
    int w = idx >> 14, r = idx & 16383;
    int n = r >> 7, k = r & 127;
    int po = (w == 2 || w == 3) ? wpack32(n, k) : wpack(n, k);   // edge weights use 32x32 layout
    dst[slot[w] * 16384 + po] = (bf16_t)pa.s[w][k * 128 + n];
}

__global__ __launch_bounds__(256) void k_fuse(const float* __restrict__ mW3, const float* __restrict__ nW0,
                                              bf16_t* __restrict__ Ft) {
    int idx = blockIdx.x * 256 + threadIdx.x;   // < 16384
    int n = idx >> 7, k = idx & 127;
    float s = 0.f;
    for (int j = 0; j < 128; j++) s += mW3[k * 128 + j] * nW0[(256 + j) * 128 + n];
    Ft[wpack(n, k)] = (bf16_t)s;
}

__global__ __launch_bounds__(128) void k_bias(const float* __restrict__ nb0, const float* __restrict__ mb3,
                                              const float* __restrict__ nW0, float* __restrict__ bfix) {
    int n = threadIdx.x;
    float s = 0.f;
    for (int j = 0; j < 128; j++) s += mb3[j] * nW0[(256 + j) * 128 + n];
    bfix[n] = nb0[n] + 20.f * s;
}

// one launch does C2 (f32, bias=bfix), P (bf16), Q' (bf16, bias=mb0)
__global__ __launch_bounds__(256, 2) void k_simple3(const float* __restrict__ in,
                                                    const bf16_t* __restrict__ Wp,
                                                    const float* __restrict__ bfix,
                                                    const float* __restrict__ mb0,
                                                    float* __restrict__ C2,
                                                    bf16_t* __restrict__ Pd,
                                                    bf16_t* __restrict__ Qd) {
    __shared__ __align__(16) bf16_t act[16384];
    int tid = threadIdx.x;
    int sel = blockIdx.x / 324, blk = blockIdx.x - sel * 324;
    size_t i0 = (size_t)blk * 128;
    int lane = tid & 63, wid = tid >> 6;
    int wm = wid >> 1, wn = wid & 1, lrow = lane & 15, q = lane >> 4;

    stage_act_f32(act, in + i0 * 128, tid);
    __syncthreads();
    const bf16_t* W = Wp + (sel == 0 ? 9 * 16384 : (sel == 1 ? 0 : 16384));
    f32x4 acc[4][4];
    gemm128s(acc, act, W, wm, wn, lane, lrow, q);
    #pragma unroll
    for (int nt = 0; nt < 4; nt++) {
        int nb = wn * 64 + nt * 16 + q * 4;
        float4 b4 = (sel == 0) ? *(const float4*)&bfix[nb]
                  : (sel == 2) ? *(const float4*)&mb0[nb]
                               : make_float4(0.f, 0.f, 0.f, 0.f);
        #pragma unroll
        for (int mt = 0; mt < 4; mt++) {
            int m = wm * 64 + mt * 16 + lrow;
            float v0 = acc[nt][mt][0] + b4.x, v1 = acc[nt][mt][1] + b4.y;
            float v2 = acc[nt][mt][2] + b4.z, v3 = acc[nt][mt][3] + b4.w;
            if (sel == 0) {
                float4 o; o.x = v0; o.y = v1; o.z = v2; o.w = v3;
                *(float4*)(C2 + (i0 + m) * 128 + nb) = o;
            } else {
                uint2 u; u.x = pkbf(v0, v1); u.y = pkbf(v2, v3);
                bf16_t* dst = (sel == 1) ? Pd : Qd;
                *(uint2*)(dst + (i0 + m) * 128 + nb) = u;
            }
        }
    }
}

// ---------------- edge kernel: 32x32x16 MFMA, 4 blocks/CU ----------------
__global__ __launch_bounds__(256, 4) void k_edge(const bf16_t* __restrict__ P, const bf16_t* __restrict__ Q,
                                                 const int* __restrict__ src, const bf16_t* __restrict__ Wp,
                                                 const float* __restrict__ mb1, const float* __restrict__ mb2,
                                                 bf16_t* __restrict__ SA) {
    __shared__ __align__(16) bf16_t act[16384];
    int tid = threadIdx.x;
    int g = blockIdx.x, b = blockIdx.y;
    int e0 = g * 120, n0 = g * 6;
    int nreal = (e0 + 120 <= EE) ? 120 : (EE - e0);   // 120 or 60
    int lane = tid & 63, wid = tid >> 6;
    int wm = wid >> 1, wn = wid & 1;

    // layer-0: act0 = relu(P[src] + Q'[dst]) (Q' has +mb0 folded), packed bf16 ops
    for (int ch = tid; ch < 2048; ch += 256) {
        int r = ch >> 4, p = ch & 15;
        uint4 o;
        if (r < nreal) {
            int e = e0 + r;
            int sn = src[e];
            int dn = n0 + r / 20;
            uint4 pv = *(const uint4*)(P + (((size_t)b * NN + sn) << 7) + (p << 3));
            uint4 qv = *(const uint4*)(Q + (((size_t)b * NN + dn) << 7) + (p << 3));
            o.x = addrelu2(pv.x, qv.x);
            o.y = addrelu2(pv.y, qv.y);
            o.z = addrelu2(pv.z, qv.z);
            o.w = addrelu2(pv.w, qv.w);
        } else {
            o.x = 0u; o.y = 0u; o.z = 0u; o.w = 0u;
        }
        *(uint4*)&act[swz(r, p << 3)] = o;
    }
    __syncthreads();

    f32x16 acc[2][2];
    gemm32x32(acc, act, Wp + 2 * 16384, mb1, wm, wn, lane);   // act0 @ mW1 + mb1
    __syncthreads();
    wb32x32(act, acc, wm, wn, lane);                          // act1 = relu
    __syncthreads();
    gemm32x32(acc, act, Wp + 3 * 16384, mb2, wm, wn, lane);   // act1 @ mW2 + mb2
    __syncthreads();
    wb32x32(act, acc, wm, wn, lane);                          // act2 = relu
    __syncthreads();

    // SA[b][n0+j][c] = sum of act2 over the node's 20 edges (2-thread split)
    if (tid < 192) {
        int j = tid >> 5;              // node 0..5
        int sub = tid & 31;
        int rr = sub >> 1;             // 8-feature chunk
        int half = sub & 1;
        int nodes = nreal / 20;
        if (j < nodes) {
            float s0 = 0.f, s1 = 0.f, s2 = 0.f, s3 = 0.f, s4 = 0.f, s5 = 0.f, s6 = 0.f, s7 = 0.f;
            #pragma unroll
            for (int i = 0; i < 10; i++) {
                int m = 20 * j + half * 10 + i;
                bf16x8 v = *(const bf16x8*)&act[swz(m, rr << 3)];
                s0 += (float)v[0]; s1 += (float)v[1]; s2 += (float)v[2]; s3 += (float)v[3];
                s4 += (float)v[4]; s5 += (float)v[5]; s6 += (float)v[6]; s7 += (float)v[7];
            }
            s0 += __shfl_xor(s0, 1); s1 += __shfl_xor(s1, 1);
            s2 += __shfl_xor(s2, 1); s3 += __shfl_xor(s3, 1);
            s4 += __shfl_xor(s4, 1); s5 += __shfl_xor(s5, 1);
            s6 += __shfl_xor(s6, 1); s7 += __shfl_xor(s7, 1);
            if (half == 0) {
                uint4 o;
                o.x = pkbf(s0, s1); o.y = pkbf(s2, s3);
                o.z = pkbf(s4, s5); o.w = pkbf(s6, s7);
                *(uint4*)(SA + (((size_t)b * NN + n0 + j) << 7) + (rr << 3)) = o;
            }
        }
    }
}

// ---------------- node kernel: M=32, 4 waves x N=32, separate SA buffer ----------------
__global__ __launch_bounds__(256, 6) void k_node(float* __restrict__ h, const bf16_t* __restrict__ SA,
                                                 const float* __restrict__ C2, const bf16_t* __restrict__ Wp,
                                                 const float* __restrict__ nb1, const float* __restrict__ nb2,
                                                 const float* __restrict__ nb3, const float* __restrict__ ln_g,
                                                 const float* __restrict__ ln_b, const float* __restrict__ mb0,
                                                 bf16_t* __restrict__ Pd, bf16_t* __restrict__ Qd) {
    __shared__ __align__(16) bf16_t act[4096];   // 32 rows x 128
    __shared__ __align__(16) bf16_t sab[4096];   // staged SA
    __shared__ float st[256];                    // 32 rows x 4 waves x {s1,s2}
    int tid = threadIdx.x;
    size_t i0 = (size_t)blockIdx.x * 32;
    int lane = tid & 63, wid = tid >> 6;
    int lrow = lane & 15, q = lane >> 4;
    int colb = wid * 32;

    // stage h (f32->bf16, packed) and SA (raw copy) in one pass
    for (int ch = tid; ch < 1024; ch += 256) {
        if (ch < 512) {
            int r = ch >> 4, p = ch & 15;
            const float4 a = *(const float4*)(h + (i0 + r) * 128 + (p << 3));
            const float4 c = *(const float4*)(h + (i0 + r) * 128 + (p << 3) + 4);
            uint4 o;
            o.x = pkbf(a.x, a.y); o.y = pkbf(a.z, a.w);
            o.z = pkbf(c.x, c.y); o.w = pkbf(c.z, c.w);
            *(uint4*)&act[swz(r, p << 3)] = o;
        } else {
            int r = (ch - 512) >> 4, p = ch & 15;
            *(uint4*)&sab[swz(r, p << 3)] = *(const uint4*)(SA + (i0 + r) * 128 + (p << 3));
        }
    }
    __syncthreads();
    f32x4 acc[2][2];
    gemm32s(acc, act, Wp + 4 * 16384, wid, lane, lrow, q, true);     // h @ nW0a
    gemm32s(acc, sab, Wp + 5 * 16384, wid, lane, lrow, q, false);    // + SA @ Ft
    __syncthreads();
    // u0 = relu(acc + C2)
    #pragma unroll
    for (int nt = 0; nt < 2; nt++) {
        int nb = colb + nt * 16 + q * 4;
        #pragma unroll
        for (int mt = 0; mt < 2; mt++) {
            int m = mt * 16 + lrow;
            float4 c4 = *(const float4*)(C2 + (i0 + m) * 128 + nb);
            uint2 u;
            u.x = pkbf_t(fmaxf(acc[nt][mt][0] + c4.x, 0.f), fmaxf(acc[nt][mt][1] + c4.y, 0.f));
            u.y = pkbf_t(fmaxf(acc[nt][mt][2] + c4.z, 0.f), fmaxf(acc[nt][mt][3] + c4.w, 0.f));
            *(uint2*)&act[swz(m, nb)] = u;
        }
    }
    __syncthreads();
    gemm32s(acc, act, Wp + 6 * 16384, wid, lane, lrow, q, true);     // nW1
    __syncthreads();
    wb32(act, acc, nb1, colb, lrow, q);
    __syncthreads();
    gemm32s(acc, act, Wp + 7 * 16384, wid, lane, lrow, q, true);     // nW2
    __syncthreads();
    wb32(act, acc, nb2, colb, lrow, q);
    __syncthreads();
    gemm32s(acc, act, Wp + 8 * 16384, wid, lane, lrow, q, true);     // nW3

    // residual v = acc + nb3 + h, LN stats
    float s1[2] = {0.f, 0.f}, s2[2] = {0.f, 0.f};
    #pragma unroll
    for (int nt = 0; nt < 2; nt++) {
        int nb = colb + nt * 16 + q * 4;
        float4 b4 = *(const float4*)&nb3[nb];
        #pragma unroll
        for (int mt = 0; mt < 2; mt++) {
            int m = mt * 16 + lrow;
            float4 h4 = *(const float4*)(h + (i0 + m) * 128 + nb);
            float v0 = acc[nt][mt][0] + b4.x + h4.x;
            float v1 = acc[nt][mt][1] + b4.y + h4.y;
            float v2 = acc[nt][mt][2] + b4.z + h4.z;
            float v3 = acc[nt][mt][3] + b4.w + h4.w;
            acc[nt][mt][0] = v0; acc[nt][mt][1] = v1;
            acc[nt][mt][2] = v2; acc[nt][mt][3] = v3;
            s1[mt] += v0 + v1 + v2 + v3;
            s2[mt] += v0 * v0 + v1 * v1 + v2 * v2 + v3 * v3;
        }
    }
    #pragma unroll
    for (int mt = 0; mt < 2; mt++) {
        float a = s1[mt], c = s2[mt];
        a += __shfl_xor(a, 16); c += __shfl_xor(c, 16);
        a += __shfl_xor(a, 32); c += __shfl_xor(c, 32);
        s1[mt] = a; s2[mt] = c;
    }
    if (q == 0) {
        #pragma unroll
        for (int mt = 0; mt < 2; mt++) {
            st[(mt * 16 + lrow) * 8 + wid * 2 + 0] = s1[mt];
            st[(mt * 16 + lrow) * 8 + wid * 2 + 1] = s2[mt];
        }
    }
    __syncthreads();
    float mu[2], rs[2];
    #pragma unroll
    for (int mt = 0; mt < 2; mt++) {
        int m = mt * 16 + lrow;
        float a = st[m * 8 + 0] + st[m * 8 + 2] + st[m * 8 + 4] + st[m * 8 + 6];
        float c = st[m * 8 + 1] + st[m * 8 + 3] + st[m * 8 + 5] + st[m * 8 + 7];
        a *= (1.f / 128.f); c *= (1.f / 128.f);
        mu[mt] = a;
        rs[mt] = rsqrtf(c - a * a + 1e-5f);
    }
    // LN apply -> h (f32) and act (bf16 for P/Q gemms)
    #pragma unroll
    for (int nt = 0; nt < 2; nt++) {
        int nb = colb + nt * 16 + q * 4;
        float4 g4 = *(const float4*)&ln_g[nb];
        float4 bb4 = *(const float4*)&ln_b[nb];
        #pragma unroll
        for (int mt = 0; mt < 2; mt++) {
            int m = mt * 16 + lrow;
            float4 o4;
            o4.x = (acc[nt][mt][0] - mu[mt]) * rs[mt] * g4.x + bb4.x;
            o4.y = (acc[nt][mt][1] - mu[mt]) * rs[mt] * g4.y + bb4.y;
            o4.z = (acc[nt][mt][2] - mu[mt]) * rs[mt] * g4.z + bb4.z;
            o4.w = (acc[nt][mt][3] - mu[mt]) * rs[mt] * g4.w + bb4.w;
            *(float4*)(h + (i0 + m) * 128 + nb) = o4;
            uint2 u;
            u.x = pkbf(o4.x, o4.y); u.y = pkbf(o4.z, o4.w);
            *(uint2*)&act[swz(m, nb)] = u;
        }
    }
    __syncthreads();
    gemm32s(acc, act, Wp + 0 * 16384, wid, lane, lrow, q, true);     // mW0a -> P
    #pragma unroll
    for (int nt = 0; nt < 2; nt++) {
        int nb = colb + nt * 16 + q * 4;
        #pragma unroll
        for (int mt = 0; mt < 2; mt++) {
            int m = mt * 16 + lrow;
            uint2 u;
            u.x = pkbf(acc[nt][mt][0], acc[nt][mt][1]);
            u.y = pkbf(acc[nt][mt][2], acc[nt][mt][3]);
            *(uint2*)(Pd + (i0 + m) * 128 + nb) = u;
        }
    }
    gemm32s(acc, act, Wp + 1 * 16384, wid, lane, lrow, q, true);     // mW0b -> Q' (+mb0)
    #pragma unroll
    for (int nt = 0; nt < 2; nt++) {
        int nb = colb + nt * 16 + q * 4;
        float4 m4 = *(const float4*)&mb0[nb];
        #pragma unroll
        for (int mt = 0; mt < 2; mt++) {
            int m = mt * 16 + lrow;
            uint2 u;
            u.x = pkbf(acc[nt][mt][0] + m4.x, acc[nt][mt][1] + m4.y);
            u.y = pkbf(acc[nt][mt][2] + m4.z, acc[nt][mt][3] + m4.w);
            *(uint2*)(Qd + (i0 + m) * 128 + nb) = u;
        }
    }
}

__global__ __launch_bounds__(256) void k_out(const float* __restrict__ h, const float* __restrict__ W_out,
                                             const float* __restrict__ b_out, float* __restrict__ out) {
    int idx = blockIdx.x * 256 + threadIdx.x;   // < BN*9
    int row = idx / 9, o = idx - row * 9;
    const float4* h4 = (const float4*)(h + (size_t)row * 128);
    float s = b_out[o];
    #pragma unroll 8
    for (int k4 = 0; k4 < 32; k4++) {
        float4 v = h4[k4];
        int kb = k4 * 4;
        s += v.x * W_out[kb * 9 + o] + v.y * W_out[(kb + 1) * 9 + o]
           + v.z * W_out[(kb + 2) * 9 + o] + v.w * W_out[(kb + 3) * 9 + o];
    }
    out[idx] = s;
}

extern "C" void kernel_launch(void* const* d_in, const int* in_sizes, int n_in,
                              void* d_out, int out_size, void* d_ws, size_t ws_size,
                              hipStream_t stream) {
    const float* x    = (const float*)d_in[0];
    const int*   src  = (const int*)d_in[1];
    const float* W_in = (const float*)d_in[3];
    const float* b_in = (const float*)d_in[4];
    const float* pos  = (const float*)d_in[5];
    const float* mW0  = (const float*)d_in[6];
    const float* mb0  = (const float*)d_in[7];
    const float* mW1  = (const float*)d_in[8];
    const float* mb1  = (const float*)d_in[9];
    const float* mW2  = (const float*)d_in[10];
    const float* mb2  = (const float*)d_in[11];
    const float* mW3  = (const float*)d_in[12];
    const float* mb3  = (const float*)d_in[13];
    const float* nW0  = (const float*)d_in[14];
    const float* nb0  = (const float*)d_in[15];
    const float* nW1  = (const float*)d_in[16];
    const float* nb1  = (const float*)d_in[17];
    const float* nW2  = (const float*)d_in[18];
    const float* nb2  = (const float*)d_in[19];
    const float* nW3  = (const float*)d_in[20];
    const float* nb3  = (const float*)d_in[21];
    const float* ln_g = (const float*)d_in[22];
    const float* ln_b = (const float*)d_in[23];
    const float* W_out= (const float*)d_in[24];
    const float* b_out= (const float*)d_in[25];

    char* ws = (char*)d_ws;
    float*  h   = (float*)ws;                       // 21,233,664 B (also x_embed)
    float*  C2  = (float*)(ws + 21233664);          // 21,233,664 B
    bf16_t* SA  = (bf16_t*)(ws + 42467328);         // 10,616,832 B
    bf16_t* P   = (bf16_t*)(ws + 53084160);         // 10,616,832 B
    bf16_t* Q   = (bf16_t*)(ws + 63700992);         // 10,616,832 B (holds Q' = Q+mb0)
    bf16_t* Wp  = (bf16_t*)(ws + 74317824);         // 10 * 32,768 B (packed bf16)
    float*  bfix= (float*)(ws + 74645504);          // 512 B

    k_embed<<<20736, 256, 0, stream>>>(x, W_in, b_in, pos, h);

    // packed slots: 0=mW0a 1=mW0b 2=mW1(32x32) 3=mW2(32x32) 4=nW0a(h) 5=Ft 6=nW1 7=nW2 8=nW3 9=nW0b(x)
    PackArgs pa;
    pa.s[0] = mW0;  pa.s[1] = mW0 + 16384; pa.s[2] = mW1; pa.s[3] = mW2;
    pa.s[4] = nW0;  pa.s[5] = nW1;  pa.s[6] = nW2;  pa.s[7] = nW3;  pa.s[8] = nW0 + 16384;
    k_pack_all<<<576, 256, 0, stream>>>(pa, Wp);
    k_fuse<<<64, 256, 0, stream>>>(mW3, nW0, Wp + 5 * 16384);
    k_bias<<<1, 128, 0, stream>>>(nb0, mb3, nW0, bfix);

    k_simple3<<<972, 256, 0, stream>>>(h, Wp, bfix, mb0, C2, P, Q);   // C2, P0, Q'0

    for (int s = 0; s < 16; s++) {
        k_edge<<<dim3(14, 512), 256, 0, stream>>>(P, Q, src, Wp, mb1, mb2, SA);
        k_node<<<1296, 256, 0, stream>>>(h, SA, C2, Wp, nb1, nb2, nb3, ln_g, ln_b, mb0, P, Q);
    }
    k_out<<<1458, 256, 0, stream>>>(h, W_out, b_out, (float*)d_out);
}

// Round 11
// 2420.124 us; speedup vs baseline: 1.1997x; 1.0007x over previous
//
#include <hip/hip_runtime.h>
#include <hip/hip_bf16.h>

typedef __bf16 bf16_t;
typedef bf16_t bf16x8 __attribute__((ext_vector_type(8)));
typedef bf16_t bf16x4 __attribute__((ext_vector_type(4)));
typedef float  f32x4  __attribute__((ext_vector_type(4)));
typedef float  f32x16 __attribute__((ext_vector_type(16)));
typedef __hip_bfloat162 bf2;

#define NN   81
#define BB   512
#define BN   41472          // 512*81
#define EE   1620

__device__ __forceinline__ int swz(int r, int k) {
    return (r << 7) + ((((k >> 3) ^ (r & 7)) << 3) | (k & 7));
}

// 16x16x32 packed-weight offset (prep + node kernels)
__device__ __forceinline__ int wpack(int n, int k) {
    return ((n >> 6) << 13) + (((((k >> 5) << 2) + ((n >> 4) & 3))) << 9)
         + (((((k >> 3) & 3) << 4) + (n & 15)) << 3) + (k & 7);
}

// 32x32x16 packed-weight offset (edge kernel)
__device__ __forceinline__ int wpack32(int n, int k) {
    return ((((k >> 4) << 2) | (n >> 5)) << 9)
         + (((((k >> 3) & 1) << 5) | (n & 31)) << 3) + (k & 7);
}

// pack two f32 -> bf16x2, round-half-up: 2 adds + 1 v_perm
__device__ __forceinline__ unsigned pkbf(float lo, float hi) {
    unsigned a = __float_as_uint(lo) + 0x8000u;
    unsigned b = __float_as_uint(hi) + 0x8000u;
    return __builtin_amdgcn_perm(b, a, 0x07060302);
}

// truncating pack (1 v_perm) — intra-step activations only
__device__ __forceinline__ unsigned pkbf_t(float lo, float hi) {
    return __builtin_amdgcn_perm(__float_as_uint(hi), __float_as_uint(lo), 0x07060302);
}

// packed bf16x2 relu(p+q)
__device__ __forceinline__ unsigned addrelu2(unsigned pd, unsigned qd) {
    unsigned zz = 0u;
    bf2 p = *(bf2*)&pd, q = *(bf2*)&qd, z = *(bf2*)&zz;
    bf2 r = __hmax2(__hadd2(p, q), z);
    return *(unsigned*)&r;
}

__device__ __forceinline__ float bflo(unsigned d) { return __uint_as_float(d << 16); }
__device__ __forceinline__ float bfhi(unsigned d) { return __uint_as_float(d & 0xffff0000u); }

// ---------------- 16x16x32 GEMM (prep + node) ----------------
__device__ __forceinline__ void gemm128s(f32x4 (&acc)[4][4], const bf16_t* act,
                                         const bf16_t* __restrict__ Wp,
                                         int wm, int wn, int lane, int lrow, int q) {
    f32x4 z = {0.f, 0.f, 0.f, 0.f};
    #pragma unroll
    for (int i = 0; i < 4; i++)
        #pragma unroll
        for (int j = 0; j < 4; j++) acc[i][j] = z;
    const bf16_t* wbase = Wp + (wn << 13) + (lane << 3);
    #pragma unroll
    for (int k0 = 0; k0 < 128; k0 += 32) {
        bf16x8 af[4], wf[4];
        #pragma unroll
        for (int mt = 0; mt < 4; mt++)
            af[mt] = *(const bf16x8*)&act[swz(wm * 64 + mt * 16 + lrow, k0 + q * 8)];
        #pragma unroll
        for (int nt = 0; nt < 4; nt++)
            wf[nt] = *(const bf16x8*)(wbase + ((((k0 >> 5) << 2) + nt) << 9));
        #pragma unroll
        for (int nt = 0; nt < 4; nt++)
            #pragma unroll
            for (int mt = 0; mt < 4; mt++)
                acc[nt][mt] = __builtin_amdgcn_mfma_f32_16x16x32_bf16(wf[nt], af[mt], acc[nt][mt], 0, 0, 0);
    }
}

// ---------------- 32x32x16 GEMM (edge): wave tile 64m x 64n, bias-init ----------------
__device__ __forceinline__ void gemm32x32(f32x16 (&acc)[2][2], const bf16_t* act,
                                          const bf16_t* __restrict__ Wp,
                                          const float* __restrict__ bias,
                                          int wm, int wn, int lane) {
    int lm = lane & 31, h = lane >> 5;
    #pragma unroll
    for (int nt = 0; nt < 2; nt++)
        #pragma unroll
        for (int g = 0; g < 4; g++) {
            float4 b4 = *(const float4*)&bias[wn * 64 + nt * 32 + 8 * g + 4 * h];
            #pragma unroll
            for (int mt = 0; mt < 2; mt++) {
                acc[nt][mt][4 * g + 0] = b4.x; acc[nt][mt][4 * g + 1] = b4.y;
                acc[nt][mt][4 * g + 2] = b4.z; acc[nt][mt][4 * g + 3] = b4.w;
            }
        }
    const bf16_t* wl = Wp + ((wn * 2) << 9) + (lane << 3);
    #pragma unroll
    for (int kk = 0; kk < 8; kk++) {
        bf16x8 af[2], wf[2];
        #pragma unroll
        for (int mt = 0; mt < 2; mt++)
            af[mt] = *(const bf16x8*)&act[swz(wm * 64 + mt * 32 + lm, kk * 16 + h * 8)];
        #pragma unroll
        for (int nt = 0; nt < 2; nt++)
            wf[nt] = *(const bf16x8*)(wl + (((kk << 2) + nt) << 9));
        #pragma unroll
        for (int nt = 0; nt < 2; nt++)
            #pragma unroll
            for (int mt = 0; mt < 2; mt++)
                acc[nt][mt] = __builtin_amdgcn_mfma_f32_32x32x16_bf16(wf[nt], af[mt], acc[nt][mt], 0, 0, 0);
    }
}

// relu writeback for 32x32 D-layout
__device__ __forceinline__ void wb32x32(bf16_t* act, f32x16 (&acc)[2][2], int wm, int wn, int lane) {
    int lm = lane & 31, h = lane >> 5;
    #pragma unroll
    for (int nt = 0; nt < 2; nt++)
        #pragma unroll
        for (int g = 0; g < 4; g++) {
            int nb = wn * 64 + nt * 32 + 8 * g + 4 * h;
            #pragma unroll
            for (int mt = 0; mt < 2; mt++) {
                int m = wm * 64 + mt * 32 + lm;
                uint2 u;
                u.x = pkbf_t(fmaxf(acc[nt][mt][4 * g + 0], 0.f), fmaxf(acc[nt][mt][4 * g + 1], 0.f));
                u.y = pkbf_t(fmaxf(acc[nt][mt][4 * g + 2], 0.f), fmaxf(acc[nt][mt][4 * g + 3], 0.f));
                *(uint2*)&act[swz(m, nb)] = u;
            }
        }
}

// ---------------- node-kernel GEMM: wave tile 32(M) x 32(N) ----------------
__device__ __forceinline__ void gemm32s(f32x4 (&acc)[2][2], const bf16_t* act,
                                        const bf16_t* __restrict__ Wp,
                                        int wid, int lane, int lrow, int q, bool zero) {
    if (zero) {
        f32x4 z = {0.f, 0.f, 0.f, 0.f};
        acc[0][0] = z; acc[0][1] = z; acc[1][0] = z; acc[1][1] = z;
    }
    int wn = wid >> 1, ntb = (wid & 1) << 1;
    const bf16_t* wbase = Wp + (wn << 13) + (lane << 3);
    #pragma unroll
    for (int k0 = 0; k0 < 128; k0 += 32) {
        bf16x8 af[2], wf[2];
        af[0] = *(const bf16x8*)&act[swz(lrow, k0 + q * 8)];
        af[1] = *(const bf16x8*)&act[swz(16 + lrow, k0 + q * 8)];
        wf[0] = *(const bf16x8*)(wbase + ((((k0 >> 5) << 2) + ntb) << 9));
        wf[1] = *(const bf16x8*)(wbase + ((((k0 >> 5) << 2) + ntb + 1) << 9));
        #pragma unroll
        for (int nt = 0; nt < 2; nt++)
            #pragma unroll
            for (int mt = 0; mt < 2; mt++)
                acc[nt][mt] = __builtin_amdgcn_mfma_f32_16x16x32_bf16(wf[nt], af[mt], acc[nt][mt], 0, 0, 0);
    }
}

__device__ __forceinline__ void wb32(bf16_t* act, f32x4 (&acc)[2][2], const float* __restrict__ bias,
                                     int colb, int lrow, int q) {
    #pragma unroll
    for (int nt = 0; nt < 2; nt++) {
        int nb = colb + nt * 16 + q * 4;
        float4 b4 = *(const float4*)&bias[nb];
        #pragma unroll
        for (int mt = 0; mt < 2; mt++) {
            int m = mt * 16 + lrow;
            uint2 u;
            u.x = pkbf_t(fmaxf(acc[nt][mt][0] + b4.x, 0.f), fmaxf(acc[nt][mt][1] + b4.y, 0.f));
            u.y = pkbf_t(fmaxf(acc[nt][mt][2] + b4.z, 0.f), fmaxf(acc[nt][mt][3] + b4.w, 0.f));
            *(uint2*)&act[swz(m, nb)] = u;
        }
    }
}

// ---------------- prep kernels ----------------

__global__ __launch_bounds__(256) void k_embed(const float* __restrict__ x, const float* __restrict__ W_in,
                                               const float* __restrict__ b_in, const float* __restrict__ pos,
                                               bf16_t* __restrict__ hb) {
    int idx = blockIdx.x * 256 + threadIdx.x;   // < BN*128
    int row = idx >> 7, col = idx & 127;
    int n = row % NN;
    const float* xr = x + (size_t)row * 10;
    float s = b_in[col] + pos[n * 128 + col];
    #pragma unroll
    for (int k = 0; k < 10; k++) s += xr[k] * W_in[k * 128 + col];
    hb[idx] = (bf16_t)s;
}

struct PackArgs { const float* s[9]; };

__global__ __launch_bounds__(256) void k_pack_all(PackArgs pa, bf16_t* __restrict__ dst) {
    const int slot[9] = {0, 1, 2, 3, 4, 6, 7, 8, 9};
    int idx = blockIdx.x * 256 + threadIdx.x;   // < 9*16384
    int w = idx >> 14, r = idx & 16383;
    int n = r >> 7, k = r & 127;
    int po = (w == 2 || w == 3) ? wpack32(n, k) : wpack(n, k);   // edge weights use 32x32 layout
    dst[slot[w] * 16384 + po] = (bf16_t)pa.s[w][k * 128 + n];
}

__global__ __launch_bounds__(256) void k_fuse(const float* __restrict__ mW3, const float* __restrict__ nW0,
                                              bf16_t* __restrict__ Ft) {
    int idx = blockIdx.x * 256 + threadIdx.x;   // < 16384
    int n = idx >> 7, k = idx & 127;
    float s = 0.f;
    for (int j = 0; j < 128; j++) s += mW3[k * 128 + j] * nW0[(256 + j) * 128 + n];
    Ft[wpack(n, k)] = (bf16_t)s;
}

__global__ __launch_bounds__(128) void k_bias(const float* __restrict__ nb0, const float* __restrict__ mb3,
                                              const float* __restrict__ nW0, float* __restrict__ bfix) {
    int n = threadIdx.x;
    float s = 0.f;
    for (int j = 0; j < 128; j++) s += mb3[j] * nW0[(256 + j) * 128 + n];
    bfix[n] = nb0[n] + 20.f * s;
}

// one launch does C2 (bf16, bias=bfix), P (bf16), Q' (bf16, bias=mb0); input hb is bf16
__global__ __launch_bounds__(256, 2) void k_simple3(const bf16_t* __restrict__ in,
                                                    const bf16_t* __restrict__ Wp,
                                                    const float* __restrict__ bfix,
                                                    const float* __restrict__ mb0,
                                                    bf16_t* __restrict__ C2b,
                                                    bf16_t* __restrict__ Pd,
                                                    bf16_t* __restrict__ Qd) {
    __shared__ __align__(16) bf16_t act[16384];
    int tid = threadIdx.x;
    int sel = blockIdx.x / 324, blk = blockIdx.x - sel * 324;
    size_t i0 = (size_t)blk * 128;
    int lane = tid & 63, wid = tid >> 6;
    int wm = wid >> 1, wn = wid & 1, lrow = lane & 15, q = lane >> 4;

    for (int ch = tid; ch < 2048; ch += 256) {      // raw bf16 stage
        int r = ch >> 4, p = ch & 15;
        *(uint4*)&act[swz(r, p << 3)] = *(const uint4*)(in + (i0 + r) * 128 + (p << 3));
    }
    __syncthreads();
    const bf16_t* W = Wp + (sel == 0 ? 9 * 16384 : (sel == 1 ? 0 : 16384));
    f32x4 acc[4][4];
    gemm128s(acc, act, W, wm, wn, lane, lrow, q);
    bf16_t* dst = (sel == 0) ? C2b : ((sel == 1) ? Pd : Qd);
    #pragma unroll
    for (int nt = 0; nt < 4; nt++) {
        int nb = wn * 64 + nt * 16 + q * 4;
        float4 b4 = (sel == 0) ? *(const float4*)&bfix[nb]
                  : (sel == 2) ? *(const float4*)&mb0[nb]
                               : make_float4(0.f, 0.f, 0.f, 0.f);
        #pragma unroll
        for (int mt = 0; mt < 4; mt++) {
            int m = wm * 64 + mt * 16 + lrow;
            uint2 u;
            u.x = pkbf(acc[nt][mt][0] + b4.x, acc[nt][mt][1] + b4.y);
            u.y = pkbf(acc[nt][mt][2] + b4.z, acc[nt][mt][3] + b4.w);
            *(uint2*)(dst + (i0 + m) * 128 + nb) = u;
        }
    }
}

// ---------------- edge kernel: 32x32x16 MFMA (unchanged from r10) ----------------
__global__ __launch_bounds__(256, 4) void k_edge(const bf16_t* __restrict__ P, const bf16_t* __restrict__ Q,
                                                 const int* __restrict__ src, const bf16_t* __restrict__ Wp,
                                                 const float* __restrict__ mb1, const float* __restrict__ mb2,
                                                 bf16_t* __restrict__ SA) {
    __shared__ __align__(16) bf16_t act[16384];
    int tid = threadIdx.x;
    int g = blockIdx.x, b = blockIdx.y;
    int e0 = g * 120, n0 = g * 6;
    int nreal = (e0 + 120 <= EE) ? 120 : (EE - e0);   // 120 or 60
    int lane = tid & 63, wid = tid >> 6;
    int wm = wid >> 1, wn = wid & 1;

    for (int ch = tid; ch < 2048; ch += 256) {
        int r = ch >> 4, p = ch & 15;
        uint4 o;
        if (r < nreal) {
            int e = e0 + r;
            int sn = src[e];
            int dn = n0 + r / 20;
            uint4 pv = *(const uint4*)(P + (((size_t)b * NN + sn) << 7) + (p << 3));
            uint4 qv = *(const uint4*)(Q + (((size_t)b * NN + dn) << 7) + (p << 3));
            o.x = addrelu2(pv.x, qv.x);
            o.y = addrelu2(pv.y, qv.y);
            o.z = addrelu2(pv.z, qv.z);
            o.w = addrelu2(pv.w, qv.w);
        } else {
            o.x = 0u; o.y = 0u; o.z = 0u; o.w = 0u;
        }
        *(uint4*)&act[swz(r, p << 3)] = o;
    }
    __syncthreads();

    f32x16 acc[2][2];
    gemm32x32(acc, act, Wp + 2 * 16384, mb1, wm, wn, lane);   // act0 @ mW1 + mb1
    __syncthreads();
    wb32x32(act, acc, wm, wn, lane);                          // act1 = relu
    __syncthreads();
    gemm32x32(acc, act, Wp + 3 * 16384, mb2, wm, wn, lane);   // act1 @ mW2 + mb2
    __syncthreads();
    wb32x32(act, acc, wm, wn, lane);                          // act2 = relu
    __syncthreads();

    if (tid < 192) {
        int j = tid >> 5;
        int sub = tid & 31;
        int rr = sub >> 1;
        int half = sub & 1;
        int nodes = nreal / 20;
        if (j < nodes) {
            float s0 = 0.f, s1 = 0.f, s2 = 0.f, s3 = 0.f, s4 = 0.f, s5 = 0.f, s6 = 0.f, s7 = 0.f;
            #pragma unroll
            for (int i = 0; i < 10; i++) {
                int m = 20 * j + half * 10 + i;
                bf16x8 v = *(const bf16x8*)&act[swz(m, rr << 3)];
                s0 += (float)v[0]; s1 += (float)v[1]; s2 += (float)v[2]; s3 += (float)v[3];
                s4 += (float)v[4]; s5 += (float)v[5]; s6 += (float)v[6]; s7 += (float)v[7];
            }
            s0 += __shfl_xor(s0, 1); s1 += __shfl_xor(s1, 1);
            s2 += __shfl_xor(s2, 1); s3 += __shfl_xor(s3, 1);
            s4 += __shfl_xor(s4, 1); s5 += __shfl_xor(s5, 1);
            s6 += __shfl_xor(s6, 1); s7 += __shfl_xor(s7, 1);
            if (half == 0) {
                uint4 o;
                o.x = pkbf(s0, s1); o.y = pkbf(s2, s3);
                o.z = pkbf(s4, s5); o.w = pkbf(s6, s7);
                *(uint4*)(SA + (((size_t)b * NN + n0 + j) << 7) + (rr << 3)) = o;
            }
        }
    }
}

// ---------------- node kernel: bf16 h/C2, M=32, 4 waves x N=32 ----------------
__global__ __launch_bounds__(256, 6) void k_node(bf16_t* __restrict__ hb, const bf16_t* __restrict__ SA,
                                                 const bf16_t* __restrict__ C2b, const bf16_t* __restrict__ Wp,
                                                 const float* __restrict__ nb1, const float* __restrict__ nb2,
                                                 const float* __restrict__ nb3, const float* __restrict__ ln_g,
                                                 const float* __restrict__ ln_b, const float* __restrict__ mb0,
                                                 bf16_t* __restrict__ Pd, bf16_t* __restrict__ Qd) {
    __shared__ __align__(16) bf16_t act[4096];   // 32 rows x 128
    __shared__ __align__(16) bf16_t sab[4096];   // staged SA
    __shared__ float st[256];                    // 32 rows x 4 waves x {s1,s2}
    int tid = threadIdx.x;
    size_t i0 = (size_t)blockIdx.x * 32;
    int lane = tid & 63, wid = tid >> 6;
    int lrow = lane & 15, q = lane >> 4;
    int colb = wid * 32;

    // stage h (raw bf16 copy) and SA in one pass
    for (int ch = tid; ch < 1024; ch += 256) {
        if (ch < 512) {
            int r = ch >> 4, p = ch & 15;
            *(uint4*)&act[swz(r, p << 3)] = *(const uint4*)(hb + (i0 + r) * 128 + (p << 3));
        } else {
            int r = (ch - 512) >> 4, p = ch & 15;
            *(uint4*)&sab[swz(r, p << 3)] = *(const uint4*)(SA + (i0 + r) * 128 + (p << 3));
        }
    }
    __syncthreads();
    f32x4 acc[2][2];
    gemm32s(acc, act, Wp + 4 * 16384, wid, lane, lrow, q, true);     // h @ nW0a
    gemm32s(acc, sab, Wp + 5 * 16384, wid, lane, lrow, q, false);    // + SA @ Ft
    __syncthreads();
    // u0 = relu(acc + C2)
    #pragma unroll
    for (int nt = 0; nt < 2; nt++) {
        int nb = colb + nt * 16 + q * 4;
        #pragma unroll
        for (int mt = 0; mt < 2; mt++) {
            int m = mt * 16 + lrow;
            uint2 cv = *(const uint2*)(C2b + (i0 + m) * 128 + nb);
            uint2 u;
            u.x = pkbf_t(fmaxf(acc[nt][mt][0] + bflo(cv.x), 0.f), fmaxf(acc[nt][mt][1] + bfhi(cv.x), 0.f));
            u.y = pkbf_t(fmaxf(acc[nt][mt][2] + bflo(cv.y), 0.f), fmaxf(acc[nt][mt][3] + bfhi(cv.y), 0.f));
            *(uint2*)&act[swz(m, nb)] = u;
        }
    }
    __syncthreads();
    gemm32s(acc, act, Wp + 6 * 16384, wid, lane, lrow, q, true);     // nW1
    __syncthreads();
    wb32(act, acc, nb1, colb, lrow, q);
    __syncthreads();
    gemm32s(acc, act, Wp + 7 * 16384, wid, lane, lrow, q, true);     // nW2
    __syncthreads();
    wb32(act, acc, nb2, colb, lrow, q);
    __syncthreads();
    gemm32s(acc, act, Wp + 8 * 16384, wid, lane, lrow, q, true);     // nW3

    // residual v = acc + nb3 + h(bf16), LN stats
    float s1[2] = {0.f, 0.f}, s2[2] = {0.f, 0.f};
    #pragma unroll
    for (int nt = 0; nt < 2; nt++) {
        int nb = colb + nt * 16 + q * 4;
        float4 b4 = *(const float4*)&nb3[nb];
        #pragma unroll
        for (int mt = 0; mt < 2; mt++) {
            int m = mt * 16 + lrow;
            uint2 hv = *(const uint2*)(hb + (i0 + m) * 128 + nb);
            float v0 = acc[nt][mt][0] + b4.x + bflo(hv.x);
            float v1 = acc[nt][mt][1] + b4.y + bfhi(hv.x);
            float v2 = acc[nt][mt][2] + b4.z + bflo(hv.y);
            float v3 = acc[nt][mt][3] + b4.w + bfhi(hv.y);
            acc[nt][mt][0] = v0; acc[nt][mt][1] = v1;
            acc[nt][mt][2] = v2; acc[nt][mt][3] = v3;
            s1[mt] += v0 + v1 + v2 + v3;
            s2[mt] += v0 * v0 + v1 * v1 + v2 * v2 + v3 * v3;
        }
    }
    #pragma unroll
    for (int mt = 0; mt < 2; mt++) {
        float a = s1[mt], c = s2[mt];
        a += __shfl_xor(a, 16); c += __shfl_xor(c, 16);
        a += __shfl_xor(a, 32); c += __shfl_xor(c, 32);
        s1[mt] = a; s2[mt] = c;
    }
    if (q == 0) {
        #pragma unroll
        for (int mt = 0; mt < 2; mt++) {
            st[(mt * 16 + lrow) * 8 + wid * 2 + 0] = s1[mt];
            st[(mt * 16 + lrow) * 8 + wid * 2 + 1] = s2[mt];
        }
    }
    __syncthreads();
    float mu[2], rs[2];
    #pragma unroll
    for (int mt = 0; mt < 2; mt++) {
        int m = mt * 16 + lrow;
        float a = st[m * 8 + 0] + st[m * 8 + 2] + st[m * 8 + 4] + st[m * 8 + 6];
        float c = st[m * 8 + 1] + st[m * 8 + 3] + st[m * 8 + 5] + st[m * 8 + 7];
        a *= (1.f / 128.f); c *= (1.f / 128.f);
        mu[mt] = a;
        rs[mt] = rsqrtf(c - a * a + 1e-5f);
    }
    // LN apply -> hb (bf16 global) and act (same packed dwords)
    #pragma unroll
    for (int nt = 0; nt < 2; nt++) {
        int nb = colb + nt * 16 + q * 4;
        float4 g4 = *(const float4*)&ln_g[nb];
        float4 bb4 = *(const float4*)&ln_b[nb];
        #pragma unroll
        for (int mt = 0; mt < 2; mt++) {
            int m = mt * 16 + lrow;
            float o0 = (acc[nt][mt][0] - mu[mt]) * rs[mt] * g4.x + bb4.x;
            float o1 = (acc[nt][mt][1] - mu[mt]) * rs[mt] * g4.y + bb4.y;
            float o2 = (acc[nt][mt][2] - mu[mt]) * rs[mt] * g4.z + bb4.z;
            float o3 = (acc[nt][mt][3] - mu[mt]) * rs[mt] * g4.w + bb4.w;
            uint2 u;
            u.x = pkbf(o0, o1); u.y = pkbf(o2, o3);
            *(uint2*)(hb + (i0 + m) * 128 + nb) = u;
            *(uint2*)&act[swz(m, nb)] = u;
        }
    }
    __syncthreads();
    gemm32s(acc, act, Wp + 0 * 16384, wid, lane, lrow, q, true);     // mW0a -> P
    #pragma unroll
    for (int nt = 0; nt < 2; nt++) {
        int nb = colb + nt * 16 + q * 4;
        #pragma unroll
        for (int mt = 0; mt < 2; mt++) {
            int m = mt * 16 + lrow;
            uint2 u;
            u.x = pkbf(acc[nt][mt][0], acc[nt][mt][1]);
            u.y = pkbf(acc[nt][mt][2], acc[nt][mt][3]);
            *(uint2*)(Pd + (i0 + m) * 128 + nb) = u;
        }
    }
    gemm32s(acc, act, Wp + 1 * 16384, wid, lane, lrow, q, true);     // mW0b -> Q' (+mb0)
    #pragma unroll
    for (int nt = 0; nt < 2; nt++) {
        int nb = colb + nt * 16 + q * 4;
        float4 m4 = *(const float4*)&mb0[nb];
        #pragma unroll
        for (int mt = 0; mt < 2; mt++) {
            int m = mt * 16 + lrow;
            uint2 u;
            u.x = pkbf(acc[nt][mt][0] + m4.x, acc[nt][mt][1] + m4.y);
            u.y = pkbf(acc[nt][mt][2] + m4.z, acc[nt][mt][3] + m4.w);
            *(uint2*)(Qd + (i0 + m) * 128 + nb) = u;
        }
    }
}

__global__ __launch_bounds__(256) void k_out(const bf16_t* __restrict__ hb, const float* __restrict__ W_out,
                                             const float* __restrict__ b_out, float* __restrict__ out) {
    int idx = blockIdx.x * 256 + threadIdx.x;   // < BN*9
    int row = idx / 9, o = idx - row * 9;
    const bf16_t* hr = hb + (size_t)row * 128;
    float s = b_out[o];
    #pragma unroll 4
    for (int k8 = 0; k8 < 16; k8++) {
        bf16x8 v = *(const bf16x8*)(hr + k8 * 8);
        int kb = k8 * 8;
        #pragma unroll
        for (int j = 0; j < 8; j++) s += (float)v[j] * W_out[(kb + j) * 9 + o];
    }
    out[idx] = s;
}

extern "C" void kernel_launch(void* const* d_in, const int* in_sizes, int n_in,
                              void* d_out, int out_size, void* d_ws, size_t ws_size,
                              hipStream_t stream) {
    const float* x    = (const float*)d_in[0];
    const int*   src  = (const int*)d_in[1];
    const float* W_in = (const float*)d_in[3];
    const float* b_in = (const float*)d_in[4];
    const float* pos  = (const float*)d_in[5];
    const float* mW0  = (const float*)d_in[6];
    const float* mb0  = (const float*)d_in[7];
    const float* mW1  = (const float*)d_in[8];
    const float* mb1  = (const float*)d_in[9];
    const float* mW2  = (const float*)d_in[10];
    const float* mb2  = (const float*)d_in[11];
    const float* mW3  = (const float*)d_in[12];
    const float* mb3  = (const float*)d_in[13];
    const float* nW0  = (const float*)d_in[14];
    const float* nb0  = (const float*)d_in[15];
    const float* nW1  = (const float*)d_in[16];
    const float* nb1  = (const float*)d_in[17];
    const float* nW2  = (const float*)d_in[18];
    const float* nb2  = (const float*)d_in[19];
    const float* nW3  = (const float*)d_in[20];
    const float* nb3  = (const float*)d_in[21];
    const float* ln_g = (const float*)d_in[22];
    const float* ln_b = (const float*)d_in[23];
    const float* W_out= (const float*)d_in[24];
    const float* b_out= (const float*)d_in[25];

    char* ws = (char*)d_ws;
    bf16_t* hb  = (bf16_t*)ws;                      // 10,616,832 B (bf16 h; also x_embed)
    bf16_t* C2b = (bf16_t*)(ws + 10616832);         // 10,616,832 B
    bf16_t* SA  = (bf16_t*)(ws + 21233664);         // 10,616,832 B
    bf16_t* P   = (bf16_t*)(ws + 31850496);         // 10,616,832 B
    bf16_t* Q   = (bf16_t*)(ws + 42467328);         // 10,616,832 B (holds Q' = Q+mb0)
    bf16_t* Wp  = (bf16_t*)(ws + 53084160);         // 10 * 32,768 B (packed bf16)
    float*  bfix= (float*)(ws + 53411840);          // 512 B

    k_embed<<<20736, 256, 0, stream>>>(x, W_in, b_in, pos, hb);

    // packed slots: 0=mW0a 1=mW0b 2=mW1(32x32) 3=mW2(32x32) 4=nW0a(h) 5=Ft 6=nW1 7=nW2 8=nW3 9=nW0b(x)
    PackArgs pa;
    pa.s[0] = mW0;  pa.s[1] = mW0 + 16384; pa.s[2] = mW1; pa.s[3] = mW2;
    pa.s[4] = nW0;  pa.s[5] = nW1;  pa.s[6] = nW2;  pa.s[7] = nW3;  pa.s[8] = nW0 + 16384;
    k_pack_all<<<576, 256, 0, stream>>>(pa, Wp);
    k_fuse<<<64, 256, 0, stream>>>(mW3, nW0, Wp + 5 * 16384);
    k_bias<<<1, 128, 0, stream>>>(nb0, mb3, nW0, bfix);

    k_simple3<<<972, 256, 0, stream>>>(hb, Wp, bfix, mb0, C2b, P, Q);   // C2, P0, Q'0

    for (int s = 0; s < 16; s++) {
        k_edge<<<dim3(14, 512), 256, 0, stream>>>(P, Q, src, Wp, mb1, mb2, SA);
        k_node<<<1296, 256, 0, stream>>>(hb, SA, C2b, Wp, nb1, nb2, nb3, ln_g, ln_b, mb0, P, Q);
    }
    k_out<<<1458, 256, 0, stream>>>(hb, W_out, b_out, (float*)d_out);
}